// Round 1
// baseline (1468.922 us; speedup 1.0000x reference)
//
#include <hip/hip_runtime.h>
#include <math.h>

#define BB 4
#define CC 128
#define NN 4096
#define HH 64
#define WW 64
#define MIDC 32

// ---------------- zero y ----------------
__global__ __launch_bounds__(256) void zero_kernel(float4* __restrict__ p) {
  p[(size_t)blockIdx.x * 256 + threadIdx.x] = make_float4(0.f, 0.f, 0.f, 0.f);
}

// ---------------- A1: q/v 1x1 convs ----------------
// block: 64 pixels, 256 outputs (q:0..127, v:128..255); thread = 4 px x 16 co
__global__ __launch_bounds__(256) void qv_kernel(
    const float* __restrict__ x,
    const float* __restrict__ qw, const float* __restrict__ qb,
    const float* __restrict__ vw, const float* __restrict__ vb,
    float* __restrict__ qbuf, float* __restrict__ vbuf) {
  int p0 = blockIdx.x * 64;
  int b = p0 / NN, n0 = p0 % NN;
  int t = threadIdx.x;
  __shared__ float xs[CC][65];
  __shared__ float wsh[16][257];
  int j = t & 15;   // pixel quad
  int g = t >> 4;   // co group (16 co)
  for (int l = 0; l < 32; l++) {
    int idx = t + 256 * l;
    int px = idx & 63, c = idx >> 6;
    xs[c][px] = x[((size_t)b * CC + c) * NN + n0 + px];
  }
  float acc[16][4];
  for (int i = 0; i < 16; i++)
    for (int p = 0; p < 4; p++) acc[i][p] = 0.f;
  for (int kc = 0; kc < CC; kc += 16) {
    __syncthreads();
    for (int l = 0; l < 16; l++) {
      int idx = t + 256 * l;
      int kk = idx & 15, co = idx >> 4;
      float wv = (co < CC) ? qw[co * CC + kc + kk] : vw[(co - CC) * CC + kc + kk];
      wsh[kk][co] = wv;
    }
    __syncthreads();
    for (int kk = 0; kk < 16; kk++) {
      float xv[4];
      for (int p = 0; p < 4; p++) xv[p] = xs[kc + kk][4 * j + p];
      for (int i = 0; i < 16; i++) {
        float wv = wsh[kk][16 * g + i];
        for (int p = 0; p < 4; p++) acc[i][p] += wv * xv[p];
      }
    }
  }
  for (int i = 0; i < 16; i++) {
    int co = 16 * g + i;
    float bias;
    float* dst;
    if (co < CC) { bias = qb[co]; dst = qbuf + ((size_t)b * CC + co) * NN; }
    else         { bias = vb[co - CC]; dst = vbuf + ((size_t)b * CC + (co - CC)) * NN; }
    float4 o = make_float4(acc[i][0] + bias, acc[i][1] + bias,
                           acc[i][2] + bias, acc[i][3] + bias);
    *(float4*)(dst + n0 + 4 * j) = o;
  }
}

// ---------------- A2: norms + weight/bias heads ----------------
__global__ __launch_bounds__(256) void heads_kernel(
    const float* __restrict__ qbuf,
    const float* __restrict__ lw1w, const float* __restrict__ lw1b,
    const float* __restrict__ lw2w, const float* __restrict__ lw2b,
    const float* __restrict__ bw1w, const float* __restrict__ bw1b,
    const float* __restrict__ bw2w, const float* __restrict__ bw2b,
    float* __restrict__ wmap, float* __restrict__ bmap, float* __restrict__ nrm) {
  int p0 = blockIdx.x * 64;
  int b = p0 / NN, n0 = p0 % NN;
  int t = threadIdx.x;
  __shared__ float xs[CC][65];
  __shared__ float hw[MIDC][CC];
  __shared__ float hb1[MIDC];
  __shared__ float hw2[MIDC];
  __shared__ float red[4][64];
  for (int l = 0; l < 32; l++) {
    int idx = t + 256 * l;
    int px = idx & 63, c = idx >> 6;
    xs[c][px] = qbuf[((size_t)b * CC + c) * NN + n0 + px];
  }
  __syncthreads();
  int px = t & 63, g = t >> 6;
  float ssq = 0.f;
  for (int c = 32 * g; c < 32 * g + 32; c++) { float v = xs[c][px]; ssq += v * v; }
  red[g][px] = ssq;
  __syncthreads();
  if (g == 0) {
    float s = red[0][px] + red[1][px] + red[2][px] + red[3][px];
    nrm[(size_t)b * NN + n0 + px] = fmaxf(sqrtf(s), 1e-4f);
  }
  for (int head = 0; head < 2; head++) {
    const float* w1 = head ? bw1w : lw1w;
    const float* b1 = head ? bw1b : lw1b;
    const float* w2 = head ? bw2w : lw2w;
    const float* b2 = head ? bw2b : lw2b;
    __syncthreads();
    for (int idx = t; idx < MIDC * CC; idx += 256) {
      int c = idx & 127, m = idx >> 7;
      hw[m][c] = w1[m * CC + c];
    }
    if (t < MIDC) { hb1[t] = b1[t]; hw2[t] = w2[t]; }
    __syncthreads();
    float a[8];
    for (int mi = 0; mi < 8; mi++) a[mi] = hb1[8 * g + mi];
    for (int c = 0; c < CC; c++) {
      float xv = xs[c][px];
      for (int mi = 0; mi < 8; mi++) a[mi] += hw[8 * g + mi][c] * xv;
    }
    float part = 0.f;
    for (int mi = 0; mi < 8; mi++) {
      float z = a[mi];
      z = (z >= 0.f) ? z : 0.2f * z;
      part += hw2[8 * g + mi] * z;
    }
    red[g][px] = part;
    __syncthreads();
    if (g == 0) {
      float s = red[0][px] + red[1][px] + red[2][px] + red[3][px] + b2[0];
      (head ? bmap : wmap)[(size_t)b * NN + n0 + px] = s;
    }
  }
}

// ---------------- B1: L[m][n] = dot(q_m, q_n) / nrm[n] ----------------
__global__ __launch_bounds__(256) void gemm1_kernel(
    const float* __restrict__ qbuf, const float* __restrict__ nrm,
    float* __restrict__ Lb, int b0, size_t Lstride, int mb) {
  int bz = blockIdx.z, b = b0 + bz;
  const float* Q = qbuf + (size_t)b * CC * NN;
  float* L = Lb + (size_t)bz * Lstride;
  int n0 = blockIdx.x * 128;
  int mt = blockIdx.y * 128;     // row offset inside strip buffer
  int m0 = mb + mt;              // global query index base
  int t = threadIdx.x;
  __shared__ float as[32][129];
  __shared__ float bs[32][129];
  float acc[8][8];
  for (int i = 0; i < 8; i++)
    for (int jj = 0; jj < 8; jj++) acc[i][jj] = 0.f;
  int jm = t >> 4, jn = t & 15;
  for (int kc = 0; kc < CC; kc += 32) {
    __syncthreads();
    for (int l = 0; l < 16; l++) {
      int idx = t + 256 * l;
      int col = idx & 127, kr = idx >> 7;
      as[kr][col] = Q[(size_t)(kc + kr) * NN + m0 + col];
      bs[kr][col] = Q[(size_t)(kc + kr) * NN + n0 + col];
    }
    __syncthreads();
    for (int k = 0; k < 32; k++) {
      float af[8], bf[8];
      for (int i = 0; i < 4; i++) {
        af[i]     = as[k][4 * jm + i];
        af[4 + i] = as[k][64 + 4 * jm + i];
        bf[i]     = bs[k][4 * jn + i];
        bf[4 + i] = bs[k][64 + 4 * jn + i];
      }
      for (int mi = 0; mi < 8; mi++)
        for (int ni = 0; ni < 8; ni++)
          acc[mi][ni] += af[mi] * bf[ni];
    }
  }
  const float* nr = nrm + (size_t)b * NN + n0;
  float rn[8];
  for (int i = 0; i < 4; i++) { rn[i] = nr[4 * jn + i]; rn[4 + i] = nr[64 + 4 * jn + i]; }
  for (int i = 0; i < 8; i++) rn[i] = 1.0f / rn[i];
  for (int mi = 0; mi < 8; mi++) {
    int m = (mi < 4) ? (4 * jm + mi) : (64 + 4 * jm + (mi - 4));
    float* Lr = L + (size_t)(mt + m) * NN + n0;
    float4 o1 = make_float4(acc[mi][0] * rn[0], acc[mi][1] * rn[1],
                            acc[mi][2] * rn[2], acc[mi][3] * rn[3]);
    float4 o2 = make_float4(acc[mi][4] * rn[4], acc[mi][5] * rn[5],
                            acc[mi][6] * rn[6], acc[mi][7] * rn[7]);
    *(float4*)(Lr + 4 * jn) = o1;
    *(float4*)(Lr + 64 + 4 * jn) = o2;
  }
}

// ---------------- B2: per-row softmax stats ----------------
__global__ __launch_bounds__(256) void stats_kernel(
    const float* __restrict__ Lb, const float* __restrict__ wmap,
    const float* __restrict__ bmap, float* __restrict__ rstat,
    int b0, size_t Lstride, int mb) {
  int bz = blockIdx.z, b = b0 + bz;
  int mi = blockIdx.x;
  int m = mb + mi;
  const float* row = Lb + (size_t)bz * Lstride + (size_t)mi * NN;
  __shared__ float lrow[NN];
  __shared__ float red[4];
  int t = threadIdx.x;
  const float4* r4 = (const float4*)row;
  float4* l4 = (float4*)lrow;
  float psum = 0.f;
  for (int i = t; i < NN / 4; i += 256) {
    float4 vv = r4[i];
    l4[i] = vv;
    psum += vv.x + vv.y + vv.z + vv.w;
  }
  for (int off = 32; off; off >>= 1) psum += __shfl_down(psum, off, 64);
  if ((t & 63) == 0) red[t >> 6] = psum;
  __syncthreads();
  float mean = (red[0] + red[1] + red[2] + red[3]) * (1.0f / NN);
  float c1 = mean * wmap[(size_t)b * NN + m] - bmap[(size_t)b * NN + m];
  __syncthreads();
  float pmax = -1e30f;
  for (int i = t; i < NN; i += 256) {
    float l = lrow[i];
    float s = l - c1;
    float z = (s > 0.f) ? l * s : 0.f;
    pmax = fmaxf(pmax, z);
  }
  for (int off = 32; off; off >>= 1) pmax = fmaxf(pmax, __shfl_down(pmax, off, 64));
  if ((t & 63) == 0) red[t >> 6] = pmax;
  __syncthreads();
  float zmax = fmaxf(fmaxf(red[0], red[1]), fmaxf(red[2], red[3]));
  __syncthreads();
  float pz = 0.f;
  for (int i = t; i < NN; i += 256) {
    float l = lrow[i];
    float s = l - c1;
    float z = (s > 0.f) ? l * s : 0.f;
    pz += __expf(z - zmax);
  }
  for (int off = 32; off; off >>= 1) pz += __shfl_down(pz, off, 64);
  if ((t & 63) == 0) red[t >> 6] = pz;
  __syncthreads();
  if (t == 0) {
    float Z = red[0] + red[1] + red[2] + red[3];
    float4 o;
    o.x = c1; o.y = zmax; o.z = 1.0f / Z; o.w = 0.f;
    ((float4*)rstat)[(size_t)b * NN + m] = o;
  }
}

// ---------------- B3: y[c][m] += sum_n v[c][n] * t[m][n], split-K ----------------
__global__ __launch_bounds__(256) void gemm2_kernel(
    const float* __restrict__ vbuf, const float* __restrict__ Lb,
    const float* __restrict__ rstat, float* __restrict__ ybuf,
    int b0, size_t Lstride, int mb) {
  int bz = blockIdx.z, b = b0 + bz;
  const float* V = vbuf + (size_t)b * CC * NN;
  const float* L = Lb + (size_t)bz * Lstride;
  float* Y = ybuf + (size_t)b * CC * NN;
  int mt = blockIdx.x * 128;
  int m0 = mb + mt;
  int kbase = blockIdx.y * 512;
  int t = threadIdx.x;
  __shared__ float as[CC][33];   // [c][k]
  __shared__ float bs[128][33];  // [m][k]
  __shared__ float4 rs[128];
  if (t < 128) rs[t] = ((const float4*)rstat)[(size_t)b * NN + m0 + t];
  float acc[8][8];
  for (int i = 0; i < 8; i++)
    for (int jj = 0; jj < 8; jj++) acc[i][jj] = 0.f;
  int jc = t >> 4, jn = t & 15;
  for (int kc = 0; kc < 512; kc += 32) {
    int k0 = kbase + kc;
    __syncthreads();
    for (int l = 0; l < 16; l++) {
      int idx = t + 256 * l;
      int kk = idx & 31, r = idx >> 5;
      as[r][kk] = V[(size_t)r * NN + k0 + kk];
      float lv = L[(size_t)(mt + r) * NN + k0 + kk];
      float4 st = rs[r];
      float s = lv - st.x;
      float tv;
      if (s > 0.f) tv = fmaxf(__expf(lv * s - st.y) * st.z, 1e-8f);
      else tv = 1e-8f;
      bs[r][kk] = tv;
    }
    __syncthreads();
    for (int k = 0; k < 32; k++) {
      float cf[8], tf[8];
      for (int i = 0; i < 4; i++) {
        cf[i]     = as[4 * jc + i][k];
        cf[4 + i] = as[64 + 4 * jc + i][k];
        tf[i]     = bs[4 * jn + i][k];
        tf[4 + i] = bs[64 + 4 * jn + i][k];
      }
      for (int ci = 0; ci < 8; ci++)
        for (int mi2 = 0; mi2 < 8; mi2++)
          acc[ci][mi2] += cf[ci] * tf[mi2];
    }
  }
  for (int ci = 0; ci < 8; ci++) {
    int c = (ci < 4) ? (4 * jc + ci) : (64 + 4 * jc + (ci - 4));
    float* Yr = Y + (size_t)c * NN + m0;
    for (int mi2 = 0; mi2 < 8; mi2++) {
      int m = (mi2 < 4) ? (4 * jn + mi2) : (64 + 4 * jn + (mi2 - 4));
      atomicAdd(Yr + m, acc[ci][mi2]);
    }
  }
}

// ---------------- E: 3x3 conv + bias + leaky + residual ----------------
#define CICH 16
__global__ __launch_bounds__(256) void conv_kernel(
    const float* __restrict__ ybuf, const float* __restrict__ x,
    const float* __restrict__ lw, const float* __restrict__ lb,
    float* __restrict__ out) {
  int htile = blockIdx.x;  // 16 tiles of 4 rows
  int cog = blockIdx.y;    // 8 groups of 16 co
  int b = blockIdx.z;
  int h0 = htile * 4;
  int t = threadIdx.x;
  int q = t & 63;
  int pw0 = (q & 15) * 4;
  int ph = q >> 4;
  int oc = t >> 6;  // 0..3 -> 4 co each
  __shared__ float ys[CICH * 6 * 66];
  __shared__ float wsh[CICH * 16 * 9];
  float acc[4][4];
  for (int i = 0; i < 4; i++)
    for (int p = 0; p < 4; p++) acc[i][p] = 0.f;
  for (int cc = 0; cc < CC; cc += CICH) {
    __syncthreads();
    for (int idx = t; idx < CICH * 6 * 66; idx += 256) {
      int ci = idx / 396, r = idx % 396;
      int hh = r / 66, ww = r % 66;
      int h = h0 - 1 + hh, w = ww - 1;
      float v = 0.f;
      if (h >= 0 && h < HH && w >= 0 && w < WW)
        v = ybuf[(((size_t)b * CC + cc + ci) * HH + h) * WW + w];
      ys[idx] = v;
    }
    for (int idx = t; idx < CICH * 16 * 9; idx += 256) {
      int col = idx / 144, r2 = idx % 144;
      int ci = r2 / 9, tap = r2 % 9;
      wsh[ci * 144 + col * 9 + tap] =
          lw[((size_t)(cog * 16 + col) * CC + cc + ci) * 9 + tap];
    }
    __syncthreads();
    for (int ci = 0; ci < CICH; ci++) {
      float yv[3][6];
      for (int dh = 0; dh < 3; dh++)
        for (int i = 0; i < 6; i++)
          yv[dh][i] = ys[ci * 396 + (ph + dh) * 66 + pw0 + i];
      for (int co = 0; co < 4; co++) {
        const float* wp = &wsh[ci * 144 + (oc * 4 + co) * 9];
        float w00 = wp[0], w01 = wp[1], w02 = wp[2];
        float w10 = wp[3], w11 = wp[4], w12 = wp[5];
        float w20 = wp[6], w21 = wp[7], w22 = wp[8];
        for (int p = 0; p < 4; p++) {
          acc[co][p] += w00 * yv[0][p] + w01 * yv[0][p + 1] + w02 * yv[0][p + 2]
                      + w10 * yv[1][p] + w11 * yv[1][p + 1] + w12 * yv[1][p + 2]
                      + w20 * yv[2][p] + w21 * yv[2][p + 1] + w22 * yv[2][p + 2];
        }
      }
    }
  }
  for (int co = 0; co < 4; co++) {
    int c = cog * 16 + oc * 4 + co;
    float bv = lb[c];
    size_t base = (((size_t)b * CC + c) * HH + (h0 + ph)) * WW + pw0;
    float4 xi = *(const float4*)(x + base);
    float4 o;
    float z0 = acc[co][0] + bv; o.x = ((z0 >= 0.f) ? z0 : 0.2f * z0) + xi.x;
    float z1 = acc[co][1] + bv; o.y = ((z1 >= 0.f) ? z1 : 0.2f * z1) + xi.y;
    float z2 = acc[co][2] + bv; o.z = ((z2 >= 0.f) ? z2 : 0.2f * z2) + xi.z;
    float z3 = acc[co][3] + bv; o.w = ((z3 >= 0.f) ? z3 : 0.2f * z3) + xi.w;
    *(float4*)(out + base) = o;
  }
}

extern "C" void kernel_launch(void* const* d_in, const int* in_sizes, int n_in,
                              void* d_out, int out_size, void* d_ws, size_t ws_size,
                              hipStream_t stream) {
  const float* x    = (const float*)d_in[0];
  const float* q_w  = (const float*)d_in[1];
  const float* q_b  = (const float*)d_in[2];
  const float* v_w  = (const float*)d_in[3];
  const float* v_b  = (const float*)d_in[4];
  const float* lw1w = (const float*)d_in[5];
  const float* lw1b = (const float*)d_in[6];
  const float* lw2w = (const float*)d_in[7];
  const float* lw2b = (const float*)d_in[8];
  const float* bw1w = (const float*)d_in[9];
  const float* bw1b = (const float*)d_in[10];
  const float* bw2w = (const float*)d_in[11];
  const float* bw2b = (const float*)d_in[12];
  const float* linw = (const float*)d_in[13];
  const float* linb = (const float*)d_in[14];
  float* out = (float*)d_out;

  float* W = (float*)d_ws;
  const size_t BCN = (size_t)BB * CC * NN;
  const size_t BN  = (size_t)BB * NN;
  float* qbuf  = W;
  float* vbuf  = qbuf + BCN;
  float* ybuf  = vbuf + BCN;
  float* wmap  = ybuf + BCN;
  float* bmap  = wmap + BN;
  float* nrmb  = bmap + BN;
  float* rstat = nrmb + BN;          // 4*BN floats
  float* Lbase = rstat + 4 * BN;
  const size_t Lsz = (size_t)NN * NN;
  const size_t baseFloats = (size_t)(Lbase - W);
  size_t availFloats = (ws_size / 4 > baseFloats) ? (ws_size / 4 - baseFloats) : 0;

  int nT;
  int mStrip;
  if (availFloats >= 4 * Lsz)            { nT = 4; mStrip = NN; }
  else if (availFloats >= Lsz)           { nT = 1; mStrip = NN; }
  else if (availFloats >= (size_t)1024 * NN) { nT = 1; mStrip = 1024; }
  else                                   { nT = 1; mStrip = 256; }
  size_t Lstride = (nT == 4) ? Lsz : 0;

  hipLaunchKernelGGL(qv_kernel, dim3(256), dim3(256), 0, stream,
                     x, q_w, q_b, v_w, v_b, qbuf, vbuf);
  hipLaunchKernelGGL(heads_kernel, dim3(256), dim3(256), 0, stream,
                     qbuf, lw1w, lw1b, lw2w, lw2b, bw1w, bw1b, bw2w, bw2b,
                     wmap, bmap, nrmb);
  hipLaunchKernelGGL(zero_kernel, dim3((unsigned)(BCN / 1024)), dim3(256), 0, stream,
                     (float4*)ybuf);

  for (int b0 = 0; b0 < BB; b0 += nT) {
    for (int mb = 0; mb < NN; mb += mStrip) {
      hipLaunchKernelGGL(gemm1_kernel, dim3(32, mStrip / 128, nT), dim3(256), 0, stream,
                         qbuf, nrmb, Lbase, b0, Lstride, mb);
      hipLaunchKernelGGL(stats_kernel, dim3(mStrip, 1, nT), dim3(256), 0, stream,
                         Lbase, wmap, bmap, rstat, b0, Lstride, mb);
      hipLaunchKernelGGL(gemm2_kernel, dim3(mStrip / 128, 8, nT), dim3(256), 0, stream,
                         vbuf, Lbase, rstat, ybuf, b0, Lstride, mb);
    }
  }
  hipLaunchKernelGGL(conv_kernel, dim3(16, 8, BB), dim3(256), 0, stream,
                     ybuf, x, linw, linb, out);
}

// Round 2
// 608.490 us; speedup vs baseline: 2.4140x; 2.4140x over previous
//
#include <hip/hip_runtime.h>
#include <math.h>

#define BB 4
#define CC 128
#define NN 4096
#define HH 64
#define WW 64
#define MIDC 32
#define SSPLIT 16
#define KCH (NN / SSPLIT)

typedef __attribute__((ext_vector_type(8))) short bf16x8;
typedef __attribute__((ext_vector_type(4))) float f32x4;

__device__ inline unsigned short f2bf(float f) {
  unsigned int u = __float_as_uint(f);
  unsigned int r = (u + 0x7FFFu + ((u >> 16) & 1u)) >> 16;
  return (unsigned short)r;
}

// ---------------- A1: q/v 1x1 convs (q fp32, v bf16) ----------------
__global__ __launch_bounds__(256) void qv_kernel(
    const float* __restrict__ x,
    const float* __restrict__ qw, const float* __restrict__ qb,
    const float* __restrict__ vw, const float* __restrict__ vb,
    float* __restrict__ qbuf, unsigned short* __restrict__ vbuf) {
  int p0 = blockIdx.x * 64;
  int b = p0 / NN, n0 = p0 % NN;
  int t = threadIdx.x;
  __shared__ float xs[CC][65];
  __shared__ float wsh[16][257];
  int j = t & 15;
  int g = t >> 4;
  for (int l = 0; l < 32; l++) {
    int idx = t + 256 * l;
    int px = idx & 63, c = idx >> 6;
    xs[c][px] = x[((size_t)b * CC + c) * NN + n0 + px];
  }
  float acc[16][4];
  for (int i = 0; i < 16; i++)
    for (int p = 0; p < 4; p++) acc[i][p] = 0.f;
  for (int kc = 0; kc < CC; kc += 16) {
    __syncthreads();
    for (int l = 0; l < 16; l++) {
      int idx = t + 256 * l;
      int kk = idx & 15, co = idx >> 4;
      float wv = (co < CC) ? qw[co * CC + kc + kk] : vw[(co - CC) * CC + kc + kk];
      wsh[kk][co] = wv;
    }
    __syncthreads();
    for (int kk = 0; kk < 16; kk++) {
      float xv[4];
      for (int p = 0; p < 4; p++) xv[p] = xs[kc + kk][4 * j + p];
      for (int i = 0; i < 16; i++) {
        float wv = wsh[kk][16 * g + i];
        for (int p = 0; p < 4; p++) acc[i][p] += wv * xv[p];
      }
    }
  }
  for (int i = 0; i < 16; i++) {
    int co = 16 * g + i;
    if (co < CC) {
      float bias = qb[co];
      float* dst = qbuf + ((size_t)b * CC + co) * NN;
      float4 o = make_float4(acc[i][0] + bias, acc[i][1] + bias,
                             acc[i][2] + bias, acc[i][3] + bias);
      *(float4*)(dst + n0 + 4 * j) = o;
    } else {
      int cv = co - CC;
      float bias = vb[cv];
      unsigned short* dst = vbuf + ((size_t)b * CC + cv) * NN + n0 + 4 * j;
      uint2 pk;
      pk.x = (unsigned int)f2bf(acc[i][0] + bias) |
             ((unsigned int)f2bf(acc[i][1] + bias) << 16);
      pk.y = (unsigned int)f2bf(acc[i][2] + bias) |
             ((unsigned int)f2bf(acc[i][3] + bias) << 16);
      *(uint2*)dst = pk;
    }
  }
}

// ---------------- A2: norms + weight/bias heads ----------------
__global__ __launch_bounds__(256) void heads_kernel(
    const float* __restrict__ qbuf,
    const float* __restrict__ lw1w, const float* __restrict__ lw1b,
    const float* __restrict__ lw2w, const float* __restrict__ lw2b,
    const float* __restrict__ bw1w, const float* __restrict__ bw1b,
    const float* __restrict__ bw2w, const float* __restrict__ bw2b,
    float* __restrict__ wmap, float* __restrict__ bmap, float* __restrict__ nrm) {
  int p0 = blockIdx.x * 64;
  int b = p0 / NN, n0 = p0 % NN;
  int t = threadIdx.x;
  __shared__ float xs[CC][65];
  __shared__ float hw[MIDC][CC];
  __shared__ float hb1[MIDC];
  __shared__ float hw2[MIDC];
  __shared__ float red[4][64];
  for (int l = 0; l < 32; l++) {
    int idx = t + 256 * l;
    int px = idx & 63, c = idx >> 6;
    xs[c][px] = qbuf[((size_t)b * CC + c) * NN + n0 + px];
  }
  __syncthreads();
  int px = t & 63, g = t >> 6;
  float ssq = 0.f;
  for (int c = 32 * g; c < 32 * g + 32; c++) { float v = xs[c][px]; ssq += v * v; }
  red[g][px] = ssq;
  __syncthreads();
  if (g == 0) {
    float s = red[0][px] + red[1][px] + red[2][px] + red[3][px];
    nrm[(size_t)b * NN + n0 + px] = fmaxf(sqrtf(s), 1e-4f);
  }
  for (int head = 0; head < 2; head++) {
    const float* w1 = head ? bw1w : lw1w;
    const float* b1 = head ? bw1b : lw1b;
    const float* w2 = head ? bw2w : lw2w;
    const float* b2 = head ? bw2b : lw2b;
    __syncthreads();
    for (int idx = t; idx < MIDC * CC; idx += 256) {
      int c = idx & 127, m = idx >> 7;
      hw[m][c] = w1[m * CC + c];
    }
    if (t < MIDC) { hb1[t] = b1[t]; hw2[t] = w2[t]; }
    __syncthreads();
    float a[8];
    for (int mi = 0; mi < 8; mi++) a[mi] = hb1[8 * g + mi];
    for (int c = 0; c < CC; c++) {
      float xv = xs[c][px];
      for (int mi = 0; mi < 8; mi++) a[mi] += hw[8 * g + mi][c] * xv;
    }
    float part = 0.f;
    for (int mi = 0; mi < 8; mi++) {
      float z = a[mi];
      z = (z >= 0.f) ? z : 0.2f * z;
      part += hw2[8 * g + mi] * z;
    }
    red[g][px] = part;
    __syncthreads();
    if (g == 0) {
      float s = red[0][px] + red[1][px] + red[2][px] + red[3][px] + b2[0];
      (head ? bmap : wmap)[(size_t)b * NN + n0 + px] = s;
    }
  }
}

// ---------------- prep: transpose q -> qt bf16 [b][n][c], zero rowsum ------
__global__ __launch_bounds__(256) void prep_kernel(
    const float* __restrict__ qbuf, unsigned short* __restrict__ qt,
    float* __restrict__ rowsum) {
  int b = blockIdx.y;
  int n0 = blockIdx.x * 64;
  int t = threadIdx.x;
  int tid = (blockIdx.y * gridDim.x + blockIdx.x) * 256 + t;
  if (tid < BB * NN) rowsum[tid] = 0.f;
  __shared__ float xs[CC][65];
  for (int l = 0; l < 32; l++) {
    int idx = t + 256 * l;
    int px = idx & 63, c = idx >> 6;
    xs[c][px] = qbuf[((size_t)b * CC + c) * NN + n0 + px];
  }
  __syncthreads();
  int n = t & 63, chalf = t >> 6;
  unsigned int* q32 = (unsigned int*)qt;
  size_t rowbase = ((size_t)b * NN + n0 + n) * CC + 32 * chalf;
  for (int i = 0; i < 32; i += 2) {
    unsigned int pk = (unsigned int)f2bf(xs[32 * chalf + i][n]) |
                      ((unsigned int)f2bf(xs[32 * chalf + i + 1][n]) << 16);
    q32[(rowbase + i) >> 1] = pk;
  }
}

// ---------------- B1: MFMA gemm1: L[m][n] = (q_m . q_n)/nrm[n], + rowsum ----
__global__ __launch_bounds__(256) void gemm1_kernel(
    const unsigned short* __restrict__ qt, const float* __restrict__ nrm,
    float* __restrict__ Lb, float* __restrict__ rowsum, int mb, int mStrip) {
  int b = blockIdx.z;
  int n0 = blockIdx.x * 128;
  int mloc0 = blockIdx.y * 128;
  int mglob0 = mb + mloc0;
  int t = threadIdx.x;
  int wave = t >> 6, lane = t & 63;
  int wm = wave >> 1, wn = wave & 1;
  int row = lane & 15, oct = lane >> 4;
  const unsigned short* qtb = qt + (size_t)b * NN * CC;

  f32x4 acc[4][4];
  for (int i = 0; i < 4; i++)
    for (int j2 = 0; j2 < 4; j2++) acc[i][j2] = (f32x4)0.f;

#pragma unroll
  for (int ks = 0; ks < 4; ks++) {
    bf16x8 af[4], bf[4];
#pragma unroll
    for (int mt = 0; mt < 4; mt++)
      af[mt] = *(const bf16x8*)(qtb +
          (size_t)(mglob0 + 64 * wm + 16 * mt + row) * CC + 32 * ks + 8 * oct);
#pragma unroll
    for (int nt = 0; nt < 4; nt++)
      bf[nt] = *(const bf16x8*)(qtb +
          (size_t)(n0 + 64 * wn + 16 * nt + row) * CC + 32 * ks + 8 * oct);
#pragma unroll
    for (int mt = 0; mt < 4; mt++)
#pragma unroll
      for (int nt = 0; nt < 4; nt++)
        acc[mt][nt] = __builtin_amdgcn_mfma_f32_16x16x32_bf16(
            af[mt], bf[nt], acc[mt][nt], 0, 0, 0);
  }

  int col = lane & 15;
  float rn[4];
#pragma unroll
  for (int nt = 0; nt < 4; nt++)
    rn[nt] = 1.0f / nrm[(size_t)b * NN + n0 + 64 * wn + 16 * nt + col];

  float rowpart[4][4];
#pragma unroll
  for (int mt = 0; mt < 4; mt++) {
#pragma unroll
    for (int r = 0; r < 4; r++) {
      int mloc = mloc0 + 64 * wm + 16 * mt + 4 * oct + r;
      float* Lr = Lb + ((size_t)b * mStrip + mloc) * NN;
      float s = 0.f;
#pragma unroll
      for (int nt = 0; nt < 4; nt++) {
        float v = acc[mt][nt][r] * rn[nt];
        Lr[n0 + 64 * wn + 16 * nt + col] = v;
        s += v;
      }
      rowpart[mt][r] = s;
    }
  }
#pragma unroll
  for (int d = 1; d < 16; d <<= 1)
#pragma unroll
    for (int mt = 0; mt < 4; mt++)
#pragma unroll
      for (int r = 0; r < 4; r++)
        rowpart[mt][r] += __shfl_xor(rowpart[mt][r], d, 64);
  if ((lane & 15) == 0) {
#pragma unroll
    for (int mt = 0; mt < 4; mt++)
#pragma unroll
      for (int r = 0; r < 4; r++)
        atomicAdd(rowsum + (size_t)b * NN + mglob0 + 64 * wm + 16 * mt + 4 * oct + r,
                  rowpart[mt][r]);
  }
}

// ---------------- B2: stats + materialize T bf16 ----------------
__global__ __launch_bounds__(256) void stats_kernel(
    const float* __restrict__ Lb, const float* __restrict__ rowsum,
    const float* __restrict__ wmap, const float* __restrict__ bmap,
    unsigned short* __restrict__ T, int mb, int mStrip) {
  int m = blockIdx.x;
  int b = blockIdx.y;
  int mglob = mb + m;
  const float* rowp = Lb + ((size_t)b * mStrip + m) * NN;
  __shared__ float zrow[NN];
  __shared__ float red[4];
  int t = threadIdx.x;
  int wave = t >> 6;
  float c1 = rowsum[(size_t)b * NN + mglob] * (1.0f / NN) *
                 wmap[(size_t)b * NN + mglob] -
             bmap[(size_t)b * NN + mglob];
  float lmax = -1e30f;
  for (int i = 4 * t; i < NN; i += 1024) {
    float4 l4 = *(const float4*)(rowp + i);
    float ls[4] = {l4.x, l4.y, l4.z, l4.w};
#pragma unroll
    for (int j = 0; j < 4; j++) {
      float l = ls[j];
      float s = l - c1;
      float z = (s > 0.f) ? l * s : 0.f;
      zrow[i + j] = z;
      lmax = fmaxf(lmax, z);
    }
  }
  for (int d = 1; d < 64; d <<= 1) lmax = fmaxf(lmax, __shfl_xor(lmax, d, 64));
  if ((t & 63) == 0) red[wave] = lmax;
  __syncthreads();
  float M = fmaxf(fmaxf(red[0], red[1]), fmaxf(red[2], red[3]));
  __syncthreads();
  float psum = 0.f;
  for (int i = t; i < NN; i += 256) {
    float z = zrow[i];
    float e = __expf(z - M);
    zrow[i] = (z == 0.f) ? -e : e;
    psum += e;
  }
  for (int d = 1; d < 64; d <<= 1) psum += __shfl_xor(psum, d, 64);
  if ((t & 63) == 0) red[wave] = psum;
  __syncthreads();
  float rZ = 1.0f / (red[0] + red[1] + red[2] + red[3]);
  unsigned int* T32 = (unsigned int*)(T + ((size_t)b * mStrip + m) * NN);
  for (int i = 4 * t; i < NN; i += 1024) {
    float4 e4 = *(const float4*)(zrow + i);
    float es[4] = {e4.x, e4.y, e4.z, e4.w};
    unsigned short u[4];
#pragma unroll
    for (int j = 0; j < 4; j++) {
      float e = es[j];
      float tv = (e < 0.f) ? 1e-8f : fmaxf(e * rZ, 1e-8f);
      u[j] = f2bf(tv);
    }
    uint2 pk;
    pk.x = (unsigned int)u[0] | ((unsigned int)u[1] << 16);
    pk.y = (unsigned int)u[2] | ((unsigned int)u[3] << 16);
    *(uint2*)(T32 + (i >> 1)) = pk;
  }
}

// ---------------- B3: MFMA gemm2: P[s][c][m] = sum_n V[c][n] T[m][n] -------
__global__ __launch_bounds__(256) void gemm2_kernel(
    const unsigned short* __restrict__ vbuf, const unsigned short* __restrict__ T,
    float* __restrict__ P, int mStrip) {
  int b = blockIdx.z;
  int mt0 = blockIdx.x;
  int s = blockIdx.y;
  int t = threadIdx.x;
  int wave = t >> 6, lane = t & 63;
  int wc = wave >> 1, wm2 = wave & 1;
  int row = lane & 15, oct = lane >> 4;
  const unsigned short* Vb = vbuf + (size_t)b * CC * NN;
  const unsigned short* Tb = T + (size_t)b * mStrip * NN;
  int mbase = mt0 * 128 + 64 * wm2;
  int nb0 = s * KCH;

  f32x4 acc[4][4];
  for (int i = 0; i < 4; i++)
    for (int j2 = 0; j2 < 4; j2++) acc[i][j2] = (f32x4)0.f;

  for (int k0 = nb0; k0 < nb0 + KCH; k0 += 32) {
    bf16x8 av[4], bv[4];
#pragma unroll
    for (int ct = 0; ct < 4; ct++)
      av[ct] = *(const bf16x8*)(Vb +
          (size_t)(64 * wc + 16 * ct + row) * NN + k0 + 8 * oct);
#pragma unroll
    for (int bt = 0; bt < 4; bt++)
      bv[bt] = *(const bf16x8*)(Tb +
          (size_t)(mbase + 16 * bt + row) * NN + k0 + 8 * oct);
#pragma unroll
    for (int ct = 0; ct < 4; ct++)
#pragma unroll
      for (int bt = 0; bt < 4; bt++)
        acc[ct][bt] = __builtin_amdgcn_mfma_f32_16x16x32_bf16(
            av[ct], bv[bt], acc[ct][bt], 0, 0, 0);
  }

  float* Pb = P + ((size_t)b * SSPLIT + s) * CC * mStrip;
#pragma unroll
  for (int ct = 0; ct < 4; ct++) {
#pragma unroll
    for (int r = 0; r < 4; r++) {
      int c = 64 * wc + 16 * ct + 4 * oct + r;
#pragma unroll
      for (int bt = 0; bt < 4; bt++) {
        int mcol = mbase + 16 * bt + (lane & 15);
        Pb[(size_t)c * mStrip + mcol] = acc[ct][bt][r];
      }
    }
  }
}

// ---------------- B4: reduce partials -> ybuf ----------------
__global__ __launch_bounds__(256) void reduce_kernel(
    const float* __restrict__ P, float* __restrict__ ybuf, int mb, int mStrip) {
  size_t tid4 = ((size_t)blockIdx.x * 256 + threadIdx.x) * 4;
  int cm = CC * mStrip;
  int b = (int)(tid4 / cm);
  int rem = (int)(tid4 % cm);
  int c = rem / mStrip;
  int m = rem % mStrip;
  float4 sum = make_float4(0.f, 0.f, 0.f, 0.f);
#pragma unroll
  for (int s = 0; s < SSPLIT; s++) {
    float4 v = *(const float4*)(P + (((size_t)b * SSPLIT + s) * CC + c) * mStrip + m);
    sum.x += v.x; sum.y += v.y; sum.z += v.z; sum.w += v.w;
  }
  *(float4*)(ybuf + ((size_t)b * CC + c) * NN + mb + m) = sum;
}

// ---------------- E: 3x3 conv + bias + leaky + residual ----------------
#define CICH 16
__global__ __launch_bounds__(256) void conv_kernel(
    const float* __restrict__ ybuf, const float* __restrict__ x,
    const float* __restrict__ lw, const float* __restrict__ lb,
    float* __restrict__ out) {
  int htile = blockIdx.x;
  int cog = blockIdx.y;
  int b = blockIdx.z;
  int h0 = htile * 4;
  int t = threadIdx.x;
  int q = t & 63;
  int pw0 = (q & 15) * 4;
  int ph = q >> 4;
  int oc = t >> 6;
  __shared__ float ys[CICH * 6 * 66];
  __shared__ float wsh[CICH * 16 * 9];
  float acc[4][4];
  for (int i = 0; i < 4; i++)
    for (int p = 0; p < 4; p++) acc[i][p] = 0.f;
  for (int cc = 0; cc < CC; cc += CICH) {
    __syncthreads();
    for (int idx = t; idx < CICH * 6 * 66; idx += 256) {
      int ci = idx / 396, r = idx % 396;
      int hh = r / 66, ww = r % 66;
      int h = h0 - 1 + hh, w = ww - 1;
      float v = 0.f;
      if (h >= 0 && h < HH && w >= 0 && w < WW)
        v = ybuf[(((size_t)b * CC + cc + ci) * HH + h) * WW + w];
      ys[idx] = v;
    }
    for (int idx = t; idx < CICH * 16 * 9; idx += 256) {
      int col = idx / 144, r2 = idx % 144;
      int ci = r2 / 9, tap = r2 % 9;
      wsh[ci * 144 + col * 9 + tap] =
          lw[((size_t)(cog * 16 + col) * CC + cc + ci) * 9 + tap];
    }
    __syncthreads();
    for (int ci = 0; ci < CICH; ci++) {
      float yv[3][6];
      for (int dh = 0; dh < 3; dh++)
        for (int i = 0; i < 6; i++)
          yv[dh][i] = ys[ci * 396 + (ph + dh) * 66 + pw0 + i];
      for (int co = 0; co < 4; co++) {
        const float* wp = &wsh[ci * 144 + (oc * 4 + co) * 9];
        float w00 = wp[0], w01 = wp[1], w02 = wp[2];
        float w10 = wp[3], w11 = wp[4], w12 = wp[5];
        float w20 = wp[6], w21 = wp[7], w22 = wp[8];
        for (int p = 0; p < 4; p++) {
          acc[co][p] += w00 * yv[0][p] + w01 * yv[0][p + 1] + w02 * yv[0][p + 2]
                      + w10 * yv[1][p] + w11 * yv[1][p + 1] + w12 * yv[1][p + 2]
                      + w20 * yv[2][p] + w21 * yv[2][p + 1] + w22 * yv[2][p + 2];
        }
      }
    }
  }
  for (int co = 0; co < 4; co++) {
    int c = cog * 16 + oc * 4 + co;
    float bv = lb[c];
    size_t base = (((size_t)b * CC + c) * HH + (h0 + ph)) * WW + pw0;
    float4 xi = *(const float4*)(x + base);
    float4 o;
    float z0 = acc[co][0] + bv; o.x = ((z0 >= 0.f) ? z0 : 0.2f * z0) + xi.x;
    float z1 = acc[co][1] + bv; o.y = ((z1 >= 0.f) ? z1 : 0.2f * z1) + xi.y;
    float z2 = acc[co][2] + bv; o.z = ((z2 >= 0.f) ? z2 : 0.2f * z2) + xi.z;
    float z3 = acc[co][3] + bv; o.w = ((z3 >= 0.f) ? z3 : 0.2f * z3) + xi.w;
    *(float4*)(out + base) = o;
  }
}

extern "C" void kernel_launch(void* const* d_in, const int* in_sizes, int n_in,
                              void* d_out, int out_size, void* d_ws, size_t ws_size,
                              hipStream_t stream) {
  const float* x    = (const float*)d_in[0];
  const float* q_w  = (const float*)d_in[1];
  const float* q_b  = (const float*)d_in[2];
  const float* v_w  = (const float*)d_in[3];
  const float* v_b  = (const float*)d_in[4];
  const float* lw1w = (const float*)d_in[5];
  const float* lw1b = (const float*)d_in[6];
  const float* lw2w = (const float*)d_in[7];
  const float* lw2b = (const float*)d_in[8];
  const float* bw1w = (const float*)d_in[9];
  const float* bw1b = (const float*)d_in[10];
  const float* bw2w = (const float*)d_in[11];
  const float* bw2b = (const float*)d_in[12];
  const float* linw = (const float*)d_in[13];
  const float* linb = (const float*)d_in[14];
  float* out = (float*)d_out;

  const size_t BCN = (size_t)BB * CC * NN;   // 2,097,152
  const size_t BN  = (size_t)BB * NN;        // 16,384

  float* W = (float*)d_ws;
  float* qbuf = W;                               // BCN f32
  float* ybuf = qbuf + BCN;                      // BCN f32
  unsigned short* vb16 = (unsigned short*)(ybuf + BCN);   // BCN bf16
  unsigned short* qt   = vb16 + BCN;                      // BCN bf16
  float* wmap  = (float*)(qt + BCN);             // BN
  float* bmap  = wmap + BN;
  float* nrmb  = bmap + BN;
  float* rowsum = nrmb + BN;
  float* Lbuf  = rowsum + BN;                    // strip: BB*mStrip*NN f32 (P overlays)
  size_t baseFloats = (size_t)(Lbuf - W);

  size_t avail = ws_size / 4;
  size_t rem = (avail > baseFloats) ? avail - baseFloats : 0;
  // per unit of mStrip: L = BB*NN = 16384 f32, T = BB*NN bf16 = 8192 f32-equiv
  int mStrip = 128;
  if (rem >= (size_t)24576 * 1024)      mStrip = 1024;
  else if (rem >= (size_t)24576 * 512)  mStrip = 512;
  else if (rem >= (size_t)24576 * 256)  mStrip = 256;
  unsigned short* Tbuf = (unsigned short*)(Lbuf + (size_t)BB * mStrip * NN);
  float* Pbuf = Lbuf;  // overlay: L dead after stats; P = BB*SSPLIT*CC*mStrip <= L

  hipLaunchKernelGGL(qv_kernel, dim3(256), dim3(256), 0, stream,
                     x, q_w, q_b, v_w, v_b, qbuf, vb16);
  hipLaunchKernelGGL(heads_kernel, dim3(256), dim3(256), 0, stream,
                     qbuf, lw1w, lw1b, lw2w, lw2b, bw1w, bw1b, bw2w, bw2b,
                     wmap, bmap, nrmb);
  hipLaunchKernelGGL(prep_kernel, dim3(NN / 64, BB), dim3(256), 0, stream,
                     qbuf, qt, rowsum);

  for (int mb = 0; mb < NN; mb += mStrip) {
    hipLaunchKernelGGL(gemm1_kernel, dim3(NN / 128, mStrip / 128, BB), dim3(256),
                       0, stream, qt, nrmb, Lbuf, rowsum, mb, mStrip);
    hipLaunchKernelGGL(stats_kernel, dim3(mStrip, BB), dim3(256), 0, stream,
                       Lbuf, rowsum, wmap, bmap, Tbuf, mb, mStrip);
    hipLaunchKernelGGL(gemm2_kernel, dim3(mStrip / 128, SSPLIT, BB), dim3(256),
                       0, stream, vb16, Tbuf, Pbuf, mStrip);
    hipLaunchKernelGGL(reduce_kernel,
                       dim3((unsigned)((size_t)BB * CC * mStrip / 1024)), dim3(256),
                       0, stream, Pbuf, ybuf, mb, mStrip);
  }
  hipLaunchKernelGGL(conv_kernel, dim3(16, 8, BB), dim3(256), 0, stream,
                     ybuf, x, linw, linb, out);
}

// Round 3
// 383.910 us; speedup vs baseline: 3.8262x; 1.5850x over previous
//
#include <hip/hip_runtime.h>
#include <math.h>

#define BB 4
#define CC 128
#define NN 4096
#define HH 64
#define WW 64
#define MIDC 32
#define MBLK 32
#define YTP 4356   // 66*66 padded pixel count

typedef __attribute__((ext_vector_type(8))) short bf16x8;
typedef __attribute__((ext_vector_type(4))) float f32x4;

__device__ inline unsigned short f2bf(float f) {
  unsigned int u = __float_as_uint(f);
  unsigned int r = (u + 0x7FFFu + ((u >> 16) & 1u)) >> 16;
  return (unsigned short)r;
}

// ---------------- A1: q/v 1x1 convs (q fp32, v bf16) + SumV ----------------
__global__ __launch_bounds__(256) void qv_kernel(
    const float* __restrict__ x,
    const float* __restrict__ qw, const float* __restrict__ qb,
    const float* __restrict__ vw, const float* __restrict__ vb,
    float* __restrict__ qbuf, unsigned short* __restrict__ vbuf,
    float* __restrict__ SumV) {
  int p0 = blockIdx.x * 64;
  int b = p0 / NN, n0 = p0 % NN;
  int t = threadIdx.x;
  __shared__ float xs[CC][65];
  __shared__ float wsh[16][257];
  int j = t & 15;
  int g = t >> 4;
  for (int l = 0; l < 32; l++) {
    int idx = t + 256 * l;
    int px = idx & 63, c = idx >> 6;
    xs[c][px] = x[((size_t)b * CC + c) * NN + n0 + px];
  }
  float acc[16][4];
  for (int i = 0; i < 16; i++)
    for (int p = 0; p < 4; p++) acc[i][p] = 0.f;
  for (int kc = 0; kc < CC; kc += 16) {
    __syncthreads();
    for (int l = 0; l < 16; l++) {
      int idx = t + 256 * l;
      int kk = idx & 15, co = idx >> 4;
      float wv = (co < CC) ? qw[co * CC + kc + kk] : vw[(co - CC) * CC + kc + kk];
      wsh[kk][co] = wv;
    }
    __syncthreads();
    for (int kk = 0; kk < 16; kk++) {
      float xv[4];
      for (int p = 0; p < 4; p++) xv[p] = xs[kc + kk][4 * j + p];
      for (int i = 0; i < 16; i++) {
        float wv = wsh[kk][16 * g + i];
        for (int p = 0; p < 4; p++) acc[i][p] += wv * xv[p];
      }
    }
  }
  for (int i = 0; i < 16; i++) {
    int co = 16 * g + i;
    if (co < CC) {
      float bias = qb[co];
      float* dst = qbuf + ((size_t)b * CC + co) * NN;
      float4 o = make_float4(acc[i][0] + bias, acc[i][1] + bias,
                             acc[i][2] + bias, acc[i][3] + bias);
      *(float4*)(dst + n0 + 4 * j) = o;
    } else {
      int cv = co - CC;
      float bias = vb[cv];
      float v0 = acc[i][0] + bias, v1 = acc[i][1] + bias;
      float v2 = acc[i][2] + bias, v3 = acc[i][3] + bias;
      unsigned short* dst = vbuf + ((size_t)b * CC + cv) * NN + n0 + 4 * j;
      uint2 pk;
      pk.x = (unsigned int)f2bf(v0) | ((unsigned int)f2bf(v1) << 16);
      pk.y = (unsigned int)f2bf(v2) | ((unsigned int)f2bf(v3) << 16);
      *(uint2*)dst = pk;
      float s4 = (v0 + v1) + (v2 + v3);
      for (int d = 1; d < 16; d <<= 1) s4 += __shfl_xor(s4, d);
      if (j == 0) atomicAdd(&SumV[b * CC + cv], s4);
    }
  }
}

// ---------------- A2: norms + weight/bias heads ----------------
__global__ __launch_bounds__(256) void heads_kernel(
    const float* __restrict__ qbuf,
    const float* __restrict__ lw1w, const float* __restrict__ lw1b,
    const float* __restrict__ lw2w, const float* __restrict__ lw2b,
    const float* __restrict__ bw1w, const float* __restrict__ bw1b,
    const float* __restrict__ bw2w, const float* __restrict__ bw2b,
    float* __restrict__ wmap, float* __restrict__ bmap, float* __restrict__ nrm) {
  int p0 = blockIdx.x * 64;
  int b = p0 / NN, n0 = p0 % NN;
  int t = threadIdx.x;
  __shared__ float xs[CC][65];
  __shared__ float hw[MIDC][CC];
  __shared__ float hb1[MIDC];
  __shared__ float hw2[MIDC];
  __shared__ float red[4][64];
  for (int l = 0; l < 32; l++) {
    int idx = t + 256 * l;
    int px = idx & 63, c = idx >> 6;
    xs[c][px] = qbuf[((size_t)b * CC + c) * NN + n0 + px];
  }
  __syncthreads();
  int px = t & 63, g = t >> 6;
  float ssq = 0.f;
  for (int c = 32 * g; c < 32 * g + 32; c++) { float v = xs[c][px]; ssq += v * v; }
  red[g][px] = ssq;
  __syncthreads();
  if (g == 0) {
    float s = red[0][px] + red[1][px] + red[2][px] + red[3][px];
    nrm[(size_t)b * NN + n0 + px] = fmaxf(sqrtf(s), 1e-4f);
  }
  for (int head = 0; head < 2; head++) {
    const float* w1 = head ? bw1w : lw1w;
    const float* b1 = head ? bw1b : lw1b;
    const float* w2 = head ? bw2w : lw2w;
    const float* b2 = head ? bw2b : lw2b;
    __syncthreads();
    for (int idx = t; idx < MIDC * CC; idx += 256) {
      int c = idx & 127, m = idx >> 7;
      hw[m][c] = w1[m * CC + c];
    }
    if (t < MIDC) { hb1[t] = b1[t]; hw2[t] = w2[t]; }
    __syncthreads();
    float a[8];
    for (int mi = 0; mi < 8; mi++) a[mi] = hb1[8 * g + mi];
    for (int c = 0; c < CC; c++) {
      float xv = xs[c][px];
      for (int mi = 0; mi < 8; mi++) a[mi] += hw[8 * g + mi][c] * xv;
    }
    float part = 0.f;
    for (int mi = 0; mi < 8; mi++) {
      float z = a[mi];
      z = (z >= 0.f) ? z : 0.2f * z;
      part += hw2[8 * g + mi] * z;
    }
    red[g][px] = part;
    __syncthreads();
    if (g == 0) {
      float s = red[0][px] + red[1][px] + red[2][px] + red[3][px] + b2[0];
      (head ? bmap : wmap)[(size_t)b * NN + n0 + px] = s;
    }
  }
}

// -------- prep: transpose q -> qt (raw) and qtn (q/nrm) bf16 [b][n][c] -----
__global__ __launch_bounds__(256) void prep_kernel(
    const float* __restrict__ qbuf, const float* __restrict__ nrm,
    unsigned short* __restrict__ qt, unsigned short* __restrict__ qtn) {
  int b = blockIdx.y;
  int n0 = blockIdx.x * 64;
  int t = threadIdx.x;
  __shared__ float xs[CC][65];
  for (int l = 0; l < 32; l++) {
    int idx = t + 256 * l;
    int px = idx & 63, c = idx >> 6;
    xs[c][px] = qbuf[((size_t)b * CC + c) * NN + n0 + px];
  }
  __syncthreads();
  int n = t & 63, chalf = t >> 6;
  float sc = 1.0f / nrm[(size_t)b * NN + n0 + n];
  unsigned int* q32 = (unsigned int*)qt;
  unsigned int* qn32 = (unsigned int*)qtn;
  size_t rowbase = ((size_t)b * NN + n0 + n) * CC + 32 * chalf;
  for (int i = 0; i < 32; i += 2) {
    float a0 = xs[32 * chalf + i][n], a1 = xs[32 * chalf + i + 1][n];
    q32[(rowbase + i) >> 1] = (unsigned)f2bf(a0) | ((unsigned)f2bf(a1) << 16);
    qn32[(rowbase + i) >> 1] = (unsigned)f2bf(a0 * sc) | ((unsigned)f2bf(a1 * sc) << 16);
  }
}

// ---------------- weight repack for 3x3 conv: Wt[co][tap][ci] bf16 ---------
__global__ __launch_bounds__(256) void wrepack_kernel(
    const float* __restrict__ lw, unsigned short* __restrict__ Wt) {
  int idx = blockIdx.x * 256 + threadIdx.x;
  if (idx >= CC * 1152) return;
  int co = idx / 1152, rem = idx % 1152;
  int tap = rem >> 7, ci = rem & 127;
  Wt[idx] = f2bf(lw[(size_t)(co * CC + ci) * 9 + tap]);
}

// ---------------- fused attention: QK^T + stats + softmax + PV -------------
// block = 32 query rows (one half pixel-row) x all 4096 keys; writes Yt bf16
__global__ __launch_bounds__(256, 2) void fused_attn(
    const unsigned short* __restrict__ qt, const unsigned short* __restrict__ qtn,
    const unsigned short* __restrict__ vb16, const float* __restrict__ nrm,
    const float* __restrict__ wmap, const float* __restrict__ bmap,
    const float* __restrict__ SumV, unsigned short* __restrict__ Yt) {
  int b = blockIdx.y;
  int m0 = blockIdx.x * MBLK;
  int t = threadIdx.x;
  int wave = t >> 6, lane = t & 63;
  int col = lane & 15, oct = lane >> 4;

  __shared__ float4 statS[MBLK];
  __shared__ float redS[4][MBLK];
  __shared__ float rZS[MBLK];
  __shared__ float yS[CC][MBLK + 1];
  __shared__ float tS[4][MBLK][72];

  for (int i = t; i < CC * (MBLK + 1); i += 256) (&yS[0][0])[i] = 0.f;

  const unsigned short* qtb = qt + (size_t)b * NN * CC;
  const unsigned short* qtnb = qtn + (size_t)b * NN * CC;
  const unsigned short* Vb = vb16 + (size_t)b * CC * NN;

  // A-resident fragments: raw q_m rows
  bf16x8 A[2][4];
#pragma unroll
  for (int mt = 0; mt < 2; mt++)
#pragma unroll
    for (int ks = 0; ks < 4; ks++)
      A[mt][ks] = *(const bf16x8*)(qtb + (size_t)(m0 + 16 * mt + col) * CC + 32 * ks + 8 * oct);

  // ---- phase 1: rowsums of l ----
  float rs[2][4];
#pragma unroll
  for (int mt = 0; mt < 2; mt++)
#pragma unroll
    for (int r = 0; r < 4; r++) rs[mt][r] = 0.f;

  for (int it = 0; it < 16; it++) {
    int n0 = it * 256 + wave * 64;
    f32x4 acc[2][4];
#pragma unroll
    for (int mt = 0; mt < 2; mt++)
#pragma unroll
      for (int nt = 0; nt < 4; nt++) acc[mt][nt] = (f32x4)0.f;
#pragma unroll
    for (int nt = 0; nt < 4; nt++) {
#pragma unroll
      for (int ks = 0; ks < 4; ks++) {
        bf16x8 Bf = *(const bf16x8*)(qtnb + (size_t)(n0 + 16 * nt + col) * CC + 32 * ks + 8 * oct);
        acc[0][nt] = __builtin_amdgcn_mfma_f32_16x16x32_bf16(A[0][ks], Bf, acc[0][nt], 0, 0, 0);
        acc[1][nt] = __builtin_amdgcn_mfma_f32_16x16x32_bf16(A[1][ks], Bf, acc[1][nt], 0, 0, 0);
      }
    }
#pragma unroll
    for (int mt = 0; mt < 2; mt++)
#pragma unroll
      for (int r = 0; r < 4; r++)
        rs[mt][r] += (acc[mt][0][r] + acc[mt][1][r]) + (acc[mt][2][r] + acc[mt][3][r]);
  }
#pragma unroll
  for (int d = 1; d < 16; d <<= 1)
#pragma unroll
    for (int mt = 0; mt < 2; mt++)
#pragma unroll
      for (int r = 0; r < 4; r++) rs[mt][r] += __shfl_xor(rs[mt][r], d);
  if (col == 0) {
#pragma unroll
    for (int mt = 0; mt < 2; mt++)
#pragma unroll
      for (int r = 0; r < 4; r++) redS[wave][16 * mt + 4 * oct + r] = rs[mt][r];
  }
  __syncthreads();
  if (t < MBLK) {
    int m = t;
    size_t gm = (size_t)b * NN + m0 + m;
    float rsum = (redS[0][m] + redS[1][m]) + (redS[2][m] + redS[3][m]);
    float c1 = rsum * (1.0f / NN) * wmap[gm] - bmap[gm];
    float nm = nrm[gm];
    float zd = nm * fmaxf(nm - c1, 0.f);
    float4 s;
    s.x = c1; s.y = zd; s.z = __expf(-zd); s.w = 0.f;
    statS[m] = s;
  }
  __syncthreads();
  float4 st[2][4];
#pragma unroll
  for (int mt = 0; mt < 2; mt++)
#pragma unroll
    for (int r = 0; r < 4; r++) st[mt][r] = statS[16 * mt + 4 * oct + r];

  // ---- phase 2: recompute l, exp, PV ----
  float zp[2][4];
#pragma unroll
  for (int mt = 0; mt < 2; mt++)
#pragma unroll
    for (int r = 0; r < 4; r++) zp[mt][r] = 0.f;
  f32x4 accY[8][2];
#pragma unroll
  for (int ct = 0; ct < 8; ct++) {
    accY[ct][0] = (f32x4)0.f;
    accY[ct][1] = (f32x4)0.f;
  }
  bool didwork = false;

  for (int it = 0; it < 16; it++) {
    int n0 = it * 256 + wave * 64;
    f32x4 acc[2][4];
#pragma unroll
    for (int mt = 0; mt < 2; mt++)
#pragma unroll
      for (int nt = 0; nt < 4; nt++) acc[mt][nt] = (f32x4)0.f;
#pragma unroll
    for (int nt = 0; nt < 4; nt++) {
#pragma unroll
      for (int ks = 0; ks < 4; ks++) {
        bf16x8 Bf = *(const bf16x8*)(qtnb + (size_t)(n0 + 16 * nt + col) * CC + 32 * ks + 8 * oct);
        acc[0][nt] = __builtin_amdgcn_mfma_f32_16x16x32_bf16(A[0][ks], Bf, acc[0][nt], 0, 0, 0);
        acc[1][nt] = __builtin_amdgcn_mfma_f32_16x16x32_bf16(A[1][ks], Bf, acc[1][nt], 0, 0, 0);
      }
    }
    float fm = -1e30f;
#pragma unroll
    for (int mt = 0; mt < 2; mt++)
#pragma unroll
      for (int nt = 0; nt < 4; nt++)
#pragma unroll
        for (int r = 0; r < 4; r++) {
          float l = acc[mt][nt][r];
          float s = l - st[mt][r].x;
          float z = l * fmaxf(s, 0.f);
          fm = fmaxf(fm, z - st[mt][r].y);
        }
    if (__any(fm > -18.4207f)) {
      didwork = true;
#pragma unroll
      for (int mt = 0; mt < 2; mt++)
#pragma unroll
        for (int nt = 0; nt < 4; nt++) {
          float tv[4];
#pragma unroll
          for (int r = 0; r < 4; r++) {
            float l = acc[mt][nt][r];
            float s = l - st[mt][r].x;
            bool um = s > 0.f;
            float e = um ? __expf(l * s - st[mt][r].y) : 0.f;
            zp[mt][r] += um ? e : st[mt][r].z;
            tv[r] = e;
          }
#pragma unroll
          for (int r = 0; r < 4; r++)
            tS[wave][16 * mt + 4 * oct + r][16 * nt + col] = tv[r];
        }
#pragma unroll
      for (int kc = 0; kc < 2; kc++) {
        bf16x8 Bp[2];
#pragma unroll
        for (int mt = 0; mt < 2; mt++) {
          const float* tp = &tS[wave][16 * mt + col][kc * 32 + 8 * oct];
          float4 aa = *(const float4*)tp;
          float4 bb = *(const float4*)(tp + 4);
          union { unsigned u[4]; bf16x8 v; } cv;
          cv.u[0] = (__float_as_uint(aa.x) >> 16) | (__float_as_uint(aa.y) & 0xffff0000u);
          cv.u[1] = (__float_as_uint(aa.z) >> 16) | (__float_as_uint(aa.w) & 0xffff0000u);
          cv.u[2] = (__float_as_uint(bb.x) >> 16) | (__float_as_uint(bb.y) & 0xffff0000u);
          cv.u[3] = (__float_as_uint(bb.z) >> 16) | (__float_as_uint(bb.w) & 0xffff0000u);
          Bp[mt] = cv.v;
        }
#pragma unroll
        for (int ct = 0; ct < 8; ct++) {
          bf16x8 Ap = *(const bf16x8*)(Vb + (size_t)(16 * ct + col) * NN + n0 + kc * 32 + 8 * oct);
          accY[ct][0] = __builtin_amdgcn_mfma_f32_16x16x32_bf16(Ap, Bp[0], accY[ct][0], 0, 0, 0);
          accY[ct][1] = __builtin_amdgcn_mfma_f32_16x16x32_bf16(Ap, Bp[1], accY[ct][1], 0, 0, 0);
        }
      }
    }
  }

  // Z reduction
#pragma unroll
  for (int d = 1; d < 16; d <<= 1)
#pragma unroll
    for (int mt = 0; mt < 2; mt++)
#pragma unroll
      for (int r = 0; r < 4; r++) zp[mt][r] += __shfl_xor(zp[mt][r], d);
  if (col == 0) {
#pragma unroll
    for (int mt = 0; mt < 2; mt++)
#pragma unroll
      for (int r = 0; r < 4; r++) redS[wave][16 * mt + 4 * oct + r] = zp[mt][r];
  }
  // y partial accumulation into shared
  if (didwork) {
#pragma unroll
    for (int ct = 0; ct < 8; ct++)
#pragma unroll
      for (int mt = 0; mt < 2; mt++)
#pragma unroll
        for (int r = 0; r < 4; r++)
          atomicAdd(&yS[16 * ct + 4 * oct + r][16 * mt + col], accY[ct][mt][r]);
  }
  __syncthreads();
  if (t < MBLK) {
    float Z = (redS[0][t] + redS[1][t]) + (redS[2][t] + redS[3][t]);
    rZS[t] = 1.0f / Z;
  }
  __syncthreads();

  // epilogue: y = yS*rZ + 1e-8*SumV  -> Yt bf16 (transposed, padded)
  int p = t >> 3, cg = t & 7;
  float rZ = rZS[p];
  int gm = m0 + p;
  int h = gm >> 6, w = gm & 63;
  unsigned op[8];
#pragma unroll
  for (int i = 0; i < 16; i += 2) {
    int c0 = 16 * cg + i;
    float y0 = yS[c0][p] * rZ + 1e-8f * SumV[b * CC + c0];
    float y1 = yS[c0 + 1][p] * rZ + 1e-8f * SumV[b * CC + c0 + 1];
    op[i >> 1] = (unsigned)f2bf(y0) | ((unsigned)f2bf(y1) << 16);
  }
  unsigned short* yp = Yt + ((size_t)b * YTP + (size_t)(h + 1) * 66 + (w + 1)) * CC + 16 * cg;
  uint4 v0; v0.x = op[0]; v0.y = op[1]; v0.z = op[2]; v0.w = op[3];
  uint4 v1; v1.x = op[4]; v1.y = op[5]; v1.z = op[6]; v1.w = op[7];
  *(uint4*)yp = v0;
  *(uint4*)(yp + 8) = v1;
}

// ---------------- MFMA 3x3 conv + bias + leaky + residual ------------------
__global__ __launch_bounds__(256, 2) void conv_mfma(
    const unsigned short* __restrict__ Yt, const unsigned short* __restrict__ Wt,
    const float* __restrict__ x, const float* __restrict__ lb,
    float* __restrict__ out) {
  int h = blockIdx.x;
  int by = blockIdx.y;
  int b = blockIdx.z;
  int t = threadIdx.x;
  int wave = t >> 6, lane = t & 63;
  int col = lane & 15, oct = lane >> 4;
  int pxt = wave & 1, cohalf = wave >> 1;
  int w0 = by * 32 + pxt * 16;
  const unsigned short* Yb = Yt + (size_t)b * YTP * CC;

  f32x4 acc[4];
#pragma unroll
  for (int ct = 0; ct < 4; ct++) acc[ct] = (f32x4)0.f;

#pragma unroll
  for (int tap = 0; tap < 9; tap++) {
    int dh = tap / 3 - 1, dw = tap % 3 - 1;
    const unsigned short* ybase =
        Yb + (size_t)((h + 1 + dh) * 66 + (w0 + 1 + dw + col)) * CC;
#pragma unroll
    for (int kc = 0; kc < 4; kc++) {
      bf16x8 Af = *(const bf16x8*)(ybase + 32 * kc + 8 * oct);
#pragma unroll
      for (int ct = 0; ct < 4; ct++) {
        bf16x8 Bf = *(const bf16x8*)(Wt +
            (size_t)(cohalf * 64 + 16 * ct + col) * 1152 + tap * 128 + 32 * kc + 8 * oct);
        acc[ct] = __builtin_amdgcn_mfma_f32_16x16x32_bf16(Af, Bf, acc[ct], 0, 0, 0);
      }
    }
  }
#pragma unroll
  for (int ct = 0; ct < 4; ct++) {
    int co = cohalf * 64 + 16 * ct + col;
    float bv = lb[co];
    int n = h * 64 + w0 + 4 * oct;
    size_t base = ((size_t)b * CC + co) * NN + n;
    float4 xi = *(const float4*)(x + base);
    float4 o;
    float z0 = acc[ct][0] + bv; o.x = ((z0 >= 0.f) ? z0 : 0.2f * z0) + xi.x;
    float z1 = acc[ct][1] + bv; o.y = ((z1 >= 0.f) ? z1 : 0.2f * z1) + xi.y;
    float z2 = acc[ct][2] + bv; o.z = ((z2 >= 0.f) ? z2 : 0.2f * z2) + xi.z;
    float z3 = acc[ct][3] + bv; o.w = ((z3 >= 0.f) ? z3 : 0.2f * z3) + xi.w;
    *(float4*)(out + base) = o;
  }
}

extern "C" void kernel_launch(void* const* d_in, const int* in_sizes, int n_in,
                              void* d_out, int out_size, void* d_ws, size_t ws_size,
                              hipStream_t stream) {
  const float* x    = (const float*)d_in[0];
  const float* q_w  = (const float*)d_in[1];
  const float* q_b  = (const float*)d_in[2];
  const float* v_w  = (const float*)d_in[3];
  const float* v_b  = (const float*)d_in[4];
  const float* lw1w = (const float*)d_in[5];
  const float* lw1b = (const float*)d_in[6];
  const float* lw2w = (const float*)d_in[7];
  const float* lw2b = (const float*)d_in[8];
  const float* bw1w = (const float*)d_in[9];
  const float* bw1b = (const float*)d_in[10];
  const float* bw2w = (const float*)d_in[11];
  const float* bw2b = (const float*)d_in[12];
  const float* linw = (const float*)d_in[13];
  const float* linb = (const float*)d_in[14];
  float* out = (float*)d_out;

  const size_t BCN = (size_t)BB * CC * NN;  // 2,097,152
  const size_t BN  = (size_t)BB * NN;       // 16,384

  float* W = (float*)d_ws;
  float* qbuf = W;                                         // BCN f32
  unsigned short* vb16 = (unsigned short*)(qbuf + BCN);    // BCN bf16
  unsigned short* qt   = vb16 + BCN;                       // BCN bf16
  unsigned short* qtn  = qt + BCN;                         // BCN bf16
  unsigned short* Yt   = qtn + BCN;                        // BB*YTP*CC bf16
  unsigned short* Wt   = Yt + (size_t)BB * YTP * CC;       // CC*1152 bf16
  float* wmap = (float*)(Wt + (size_t)CC * 1152);
  float* bmap = wmap + BN;
  float* nrmb = bmap + BN;
  float* SumV = nrmb + BN;                                 // BB*CC f32

  hipMemsetAsync(SumV, 0, (size_t)BB * CC * sizeof(float), stream);
  hipMemsetAsync(Yt, 0, (size_t)BB * YTP * CC * sizeof(unsigned short), stream);

  hipLaunchKernelGGL(qv_kernel, dim3(256), dim3(256), 0, stream,
                     x, q_w, q_b, v_w, v_b, qbuf, vb16, SumV);
  hipLaunchKernelGGL(heads_kernel, dim3(256), dim3(256), 0, stream,
                     qbuf, lw1w, lw1b, lw2w, lw2b, bw1w, bw1b, bw2w, bw2b,
                     wmap, bmap, nrmb);
  hipLaunchKernelGGL(prep_kernel, dim3(NN / 64, BB), dim3(256), 0, stream,
                     qbuf, nrmb, qt, qtn);
  hipLaunchKernelGGL(wrepack_kernel, dim3((CC * 1152 + 255) / 256), dim3(256), 0,
                     stream, linw, Wt);
  hipLaunchKernelGGL(fused_attn, dim3(NN / MBLK, BB), dim3(256), 0, stream,
                     qt, qtn, vb16, nrmb, wmap, bmap, SumV, Yt);
  hipLaunchKernelGGL(conv_mfma, dim3(HH, 2, BB), dim3(256), 0, stream,
                     Yt, Wt, x, linb, out);
}

// Round 4
// 337.988 us; speedup vs baseline: 4.3461x; 1.1359x over previous
//
#include <hip/hip_runtime.h>
#include <math.h>

#define BB 4
#define CC 128
#define NN 4096
#define HH 64
#define WW 64
#define MIDC 32
#define KSL 4
#define YTP 4356   // 66*66 padded pixel count

typedef __attribute__((ext_vector_type(8))) short bf16x8;
typedef __attribute__((ext_vector_type(4))) float f32x4;

__device__ inline unsigned short f2bf(float f) {
  unsigned int u = __float_as_uint(f);
  unsigned int r = (u + 0x7FFFu + ((u >> 16) & 1u)) >> 16;
  return (unsigned short)r;
}
__device__ inline float bf2f(short s) {
  union { unsigned u; float f; } x;
  x.u = ((unsigned)(unsigned short)s) << 16;
  return x.f;
}

// ---------------- A1: q/v 1x1 convs (q fp32, v bf16) + SumV ----------------
__global__ __launch_bounds__(256) void qv_kernel(
    const float* __restrict__ x,
    const float* __restrict__ qw, const float* __restrict__ qb,
    const float* __restrict__ vw, const float* __restrict__ vb,
    float* __restrict__ qbuf, unsigned short* __restrict__ vbuf,
    float* __restrict__ SumV) {
  int p0 = blockIdx.x * 64;
  int b = p0 / NN, n0 = p0 % NN;
  int t = threadIdx.x;
  __shared__ float xs[CC][65];
  __shared__ float wsh[16][257];
  int j = t & 15;
  int g = t >> 4;
  for (int l = 0; l < 32; l++) {
    int idx = t + 256 * l;
    int px = idx & 63, c = idx >> 6;
    xs[c][px] = x[((size_t)b * CC + c) * NN + n0 + px];
  }
  float acc[16][4];
  for (int i = 0; i < 16; i++)
    for (int p = 0; p < 4; p++) acc[i][p] = 0.f;
  for (int kc = 0; kc < CC; kc += 16) {
    __syncthreads();
    for (int l = 0; l < 16; l++) {
      int idx = t + 256 * l;
      int kk = idx & 15, co = idx >> 4;
      float wv = (co < CC) ? qw[co * CC + kc + kk] : vw[(co - CC) * CC + kc + kk];
      wsh[kk][co] = wv;
    }
    __syncthreads();
    for (int kk = 0; kk < 16; kk++) {
      float xv[4];
      for (int p = 0; p < 4; p++) xv[p] = xs[kc + kk][4 * j + p];
      for (int i = 0; i < 16; i++) {
        float wv = wsh[kk][16 * g + i];
        for (int p = 0; p < 4; p++) acc[i][p] += wv * xv[p];
      }
    }
  }
  for (int i = 0; i < 16; i++) {
    int co = 16 * g + i;
    if (co < CC) {
      float bias = qb[co];
      float* dst = qbuf + ((size_t)b * CC + co) * NN;
      float4 o = make_float4(acc[i][0] + bias, acc[i][1] + bias,
                             acc[i][2] + bias, acc[i][3] + bias);
      *(float4*)(dst + n0 + 4 * j) = o;
    } else {
      int cv = co - CC;
      float bias = vb[cv];
      float v0 = acc[i][0] + bias, v1 = acc[i][1] + bias;
      float v2 = acc[i][2] + bias, v3 = acc[i][3] + bias;
      unsigned short* dst = vbuf + ((size_t)b * CC + cv) * NN + n0 + 4 * j;
      uint2 pk;
      pk.x = (unsigned int)f2bf(v0) | ((unsigned int)f2bf(v1) << 16);
      pk.y = (unsigned int)f2bf(v2) | ((unsigned int)f2bf(v3) << 16);
      *(uint2*)dst = pk;
      float s4 = (v0 + v1) + (v2 + v3);
      for (int d = 1; d < 16; d <<= 1) s4 += __shfl_xor(s4, d);
      if (j == 0) atomicAdd(&SumV[b * CC + cv], s4);
    }
  }
}

// ---------------- A2: norms + weight/bias heads ----------------
__global__ __launch_bounds__(256) void heads_kernel(
    const float* __restrict__ qbuf,
    const float* __restrict__ lw1w, const float* __restrict__ lw1b,
    const float* __restrict__ lw2w, const float* __restrict__ lw2b,
    const float* __restrict__ bw1w, const float* __restrict__ bw1b,
    const float* __restrict__ bw2w, const float* __restrict__ bw2b,
    float* __restrict__ wmap, float* __restrict__ bmap, float* __restrict__ nrm) {
  int p0 = blockIdx.x * 64;
  int b = p0 / NN, n0 = p0 % NN;
  int t = threadIdx.x;
  __shared__ float xs[CC][65];
  __shared__ float hw[MIDC][CC];
  __shared__ float hb1[MIDC];
  __shared__ float hw2[MIDC];
  __shared__ float red[4][64];
  for (int l = 0; l < 32; l++) {
    int idx = t + 256 * l;
    int px = idx & 63, c = idx >> 6;
    xs[c][px] = qbuf[((size_t)b * CC + c) * NN + n0 + px];
  }
  __syncthreads();
  int px = t & 63, g = t >> 6;
  float ssq = 0.f;
  for (int c = 32 * g; c < 32 * g + 32; c++) { float v = xs[c][px]; ssq += v * v; }
  red[g][px] = ssq;
  __syncthreads();
  if (g == 0) {
    float s = red[0][px] + red[1][px] + red[2][px] + red[3][px];
    nrm[(size_t)b * NN + n0 + px] = fmaxf(sqrtf(s), 1e-4f);
  }
  for (int head = 0; head < 2; head++) {
    const float* w1 = head ? bw1w : lw1w;
    const float* b1 = head ? bw1b : lw1b;
    const float* w2 = head ? bw2w : lw2w;
    const float* b2 = head ? bw2b : lw2b;
    __syncthreads();
    for (int idx = t; idx < MIDC * CC; idx += 256) {
      int c = idx & 127, m = idx >> 7;
      hw[m][c] = w1[m * CC + c];
    }
    if (t < MIDC) { hb1[t] = b1[t]; hw2[t] = w2[t]; }
    __syncthreads();
    float a[8];
    for (int mi = 0; mi < 8; mi++) a[mi] = hb1[8 * g + mi];
    for (int c = 0; c < CC; c++) {
      float xv = xs[c][px];
      for (int mi = 0; mi < 8; mi++) a[mi] += hw[8 * g + mi][c] * xv;
    }
    float part = 0.f;
    for (int mi = 0; mi < 8; mi++) {
      float z = a[mi];
      z = (z >= 0.f) ? z : 0.2f * z;
      part += hw2[8 * g + mi] * z;
    }
    red[g][px] = part;
    __syncthreads();
    if (g == 0) {
      float s = red[0][px] + red[1][px] + red[2][px] + red[3][px] + b2[0];
      (head ? bmap : wmap)[(size_t)b * NN + n0 + px] = s;
    }
  }
}

// -------- prep: transpose q -> qt (raw) / qtn (q/nrm) bf16 [b][n][c] + Skey
__global__ __launch_bounds__(256) void prep_kernel(
    const float* __restrict__ qbuf, const float* __restrict__ nrm,
    unsigned short* __restrict__ qt, unsigned short* __restrict__ qtn,
    float* __restrict__ Skey) {
  int b = blockIdx.y;
  int n0 = blockIdx.x * 64;
  int t = threadIdx.x;
  __shared__ float xs[CC][65];
  for (int l = 0; l < 32; l++) {
    int idx = t + 256 * l;
    int px = idx & 63, c = idx >> 6;
    xs[c][px] = qbuf[((size_t)b * CC + c) * NN + n0 + px];
  }
  __syncthreads();
  int n = t & 63, chalf = t >> 6;
  float sc = 1.0f / nrm[(size_t)b * NN + n0 + n];
  unsigned int* q32 = (unsigned int*)qt;
  unsigned int* qn32 = (unsigned int*)qtn;
  size_t rowbase = ((size_t)b * NN + n0 + n) * CC + 32 * chalf;
  float skv[32];
#pragma unroll
  for (int i = 0; i < 32; i += 2) {
    float a0 = xs[32 * chalf + i][n], a1 = xs[32 * chalf + i + 1][n];
    unsigned short u0 = f2bf(a0 * sc), u1 = f2bf(a1 * sc);
    q32[(rowbase + i) >> 1] = (unsigned)f2bf(a0) | ((unsigned)f2bf(a1) << 16);
    qn32[(rowbase + i) >> 1] = (unsigned)u0 | ((unsigned)u1 << 16);
    skv[i] = bf2f((short)u0);
    skv[i + 1] = bf2f((short)u1);
  }
#pragma unroll
  for (int i = 0; i < 32; i++) {
    float v = skv[i];
    v += __shfl_xor(v, 1);  v += __shfl_xor(v, 2);
    v += __shfl_xor(v, 4);  v += __shfl_xor(v, 8);
    v += __shfl_xor(v, 16); v += __shfl_xor(v, 32);
    if ((t & 63) == 0) atomicAdd(Skey + b * CC + 32 * chalf + i, v);
  }
}

// ---------------- weight repack for 3x3 conv: Wt[co][tap][ci] bf16 ---------
__global__ __launch_bounds__(256) void wrepack_kernel(
    const float* __restrict__ lw, unsigned short* __restrict__ Wt) {
  int idx = blockIdx.x * 256 + threadIdx.x;
  if (idx >= CC * 1152) return;
  int co = idx / 1152, rem = idx % 1152;
  int tap = rem >> 7, ci = rem & 127;
  Wt[idx] = f2bf(lw[(size_t)(co * CC + ci) * 9 + tap]);
}

// ---------------- fused attention, split-K: QK^T + softmax + PV ------------
// block = 32 m-rows x 1024 keys; wave = 32 m x 256 keys (8 iters of 32)
__global__ __launch_bounds__(256, 2) void fused_attn(
    const unsigned short* __restrict__ qt, const unsigned short* __restrict__ qtn,
    const unsigned short* __restrict__ vb16, const float* __restrict__ nrm,
    const float* __restrict__ wmap, const float* __restrict__ bmap,
    const float* __restrict__ Skey, float* __restrict__ Zacc,
    float* __restrict__ Yacc) {
  int mb = blockIdx.x, ks = blockIdx.y, b = blockIdx.z;
  int m0 = mb * 32;
  int t = threadIdx.x;
  int wave = t >> 6, lane = t & 63;
  int col = lane & 15, oct = lane >> 4;
  __shared__ unsigned short tS[4][32][40];   // per-wave P-transform buffer

  const unsigned short* qtb = qt + (size_t)b * NN * CC;
  const unsigned short* qtnb = qtn + (size_t)b * NN * CC;
  const unsigned short* Vb = vb16 + (size_t)b * CC * NN;

  // persistent A fragments: raw q rows (m0..m0+31)
  bf16x8 A[2][4];
#pragma unroll
  for (int mt = 0; mt < 2; mt++)
#pragma unroll
    for (int kc = 0; kc < 4; kc++)
      A[mt][kc] = *(const bf16x8*)(qtb + (size_t)(m0 + 16 * mt + col) * CC + 32 * kc + 8 * oct);

  // analytic rowsum -> stats (c1, zd) per row, distributed to C-layout lanes
  float stc1[2][4], stzd[2][4];
#pragma unroll
  for (int mt = 0; mt < 2; mt++) {
    float dot = 0.f;
#pragma unroll
    for (int kc = 0; kc < 4; kc++) {
      const float* skp = Skey + b * CC + 32 * kc + 8 * oct;
      float4 s0 = *(const float4*)skp;
      float4 s1 = *(const float4*)(skp + 4);
      bf16x8 a = A[mt][kc];
      dot += bf2f(a[0]) * s0.x + bf2f(a[1]) * s0.y + bf2f(a[2]) * s0.z + bf2f(a[3]) * s0.w;
      dot += bf2f(a[4]) * s1.x + bf2f(a[5]) * s1.y + bf2f(a[6]) * s1.z + bf2f(a[7]) * s1.w;
    }
    dot += __shfl_xor(dot, 16);
    dot += __shfl_xor(dot, 32);
    int m = m0 + 16 * mt + col;
    float c1 = dot * (1.0f / NN) * wmap[(size_t)b * NN + m] - bmap[(size_t)b * NN + m];
    float nm = nrm[(size_t)b * NN + m];
    float zd = nm * fmaxf(nm - c1, 0.f);   // analytic max of z over keys (Cauchy-Schwarz)
#pragma unroll
    for (int r = 0; r < 4; r++) {
      stc1[mt][r] = __shfl(c1, 4 * oct + r);
      stzd[mt][r] = __shfl(zd, 4 * oct + r);
    }
  }

  int kb = ks * (NN / KSL) + wave * (NN / KSL / 4);
  float zp[2][4];
#pragma unroll
  for (int mt = 0; mt < 2; mt++)
#pragma unroll
    for (int r = 0; r < 4; r++) zp[mt][r] = 0.f;
  f32x4 accY[8][2];
#pragma unroll
  for (int ct = 0; ct < 8; ct++) { accY[ct][0] = (f32x4)0.f; accY[ct][1] = (f32x4)0.f; }
  bool didwork = false;

  auto loadB = [&](int it, bf16x8 (&B)[2][4]) {
    int n0 = kb + it * 32;
#pragma unroll
    for (int nt = 0; nt < 2; nt++)
#pragma unroll
      for (int kc = 0; kc < 4; kc++)
        B[nt][kc] = *(const bf16x8*)(qtnb + (size_t)(n0 + 16 * nt + col) * CC + 32 * kc + 8 * oct);
  };
  auto body = [&](int it, bf16x8 (&Bc)[2][4], bf16x8 (&Bn)[2][4]) {
    if (it + 1 < 8) loadB(it + 1, Bn);
    f32x4 acc[2][2];
    acc[0][0] = (f32x4)0.f; acc[0][1] = (f32x4)0.f;
    acc[1][0] = (f32x4)0.f; acc[1][1] = (f32x4)0.f;
#pragma unroll
    for (int kc = 0; kc < 4; kc++)
#pragma unroll
      for (int mt = 0; mt < 2; mt++)
#pragma unroll
        for (int nt = 0; nt < 2; nt++)
          acc[mt][nt] = __builtin_amdgcn_mfma_f32_16x16x32_bf16(
              A[mt][kc], Bc[nt][kc], acc[mt][nt], 0, 0, 0);
    float d[2][2][4];
    float fm = -1e30f;
#pragma unroll
    for (int mt = 0; mt < 2; mt++)
#pragma unroll
      for (int nt = 0; nt < 2; nt++)
#pragma unroll
        for (int r = 0; r < 4; r++) {
          float l = acc[mt][nt][r];
          float z = l * fmaxf(l - stc1[mt][r], 0.f);
          float dd = z - stzd[mt][r];
          d[mt][nt][r] = dd;
          fm = fmaxf(fm, dd);
        }
    if (__any(fm > -18.4207f)) {   // e^-18.42 = 1e-8: below floor, provably clipped
      didwork = true;
      int n0 = kb + it * 32;
#pragma unroll
      for (int mt = 0; mt < 2; mt++)
#pragma unroll
        for (int nt = 0; nt < 2; nt++)
#pragma unroll
          for (int r = 0; r < 4; r++) {
            float ev = __expf(d[mt][nt][r]);
            zp[mt][r] += ev;
            tS[wave][16 * mt + 4 * oct + r][16 * nt + col] = f2bf(ev);
          }
      bf16x8 Bp0 = *(const bf16x8*)&tS[wave][col][8 * oct];
      bf16x8 Bp1 = *(const bf16x8*)&tS[wave][16 + col][8 * oct];
#pragma unroll
      for (int ct = 0; ct < 8; ct++) {
        bf16x8 Av = *(const bf16x8*)(Vb + (size_t)(16 * ct + col) * NN + n0 + 8 * oct);
        accY[ct][0] = __builtin_amdgcn_mfma_f32_16x16x32_bf16(Av, Bp0, accY[ct][0], 0, 0, 0);
        accY[ct][1] = __builtin_amdgcn_mfma_f32_16x16x32_bf16(Av, Bp1, accY[ct][1], 0, 0, 0);
      }
    }
  };

  bf16x8 B0[2][4], B1[2][4];
  loadB(0, B0);
  for (int it = 0; it < 8; it += 2) { body(it, B0, B1); body(it + 1, B1, B0); }

  if (didwork) {
#pragma unroll
    for (int mt = 0; mt < 2; mt++)
#pragma unroll
      for (int r = 0; r < 4; r++) {
        float v = zp[mt][r];
        v += __shfl_xor(v, 1); v += __shfl_xor(v, 2);
        v += __shfl_xor(v, 4); v += __shfl_xor(v, 8);
        if (col == 0)
          atomicAdd(Zacc + (size_t)b * NN + m0 + 16 * mt + 4 * oct + r, v);
      }
#pragma unroll
    for (int ct = 0; ct < 8; ct++)
#pragma unroll
      for (int mt = 0; mt < 2; mt++)
#pragma unroll
        for (int r = 0; r < 4; r++)
          atomicAdd(Yacc + ((size_t)b * NN + m0 + 16 * mt + col) * CC + 16 * ct + 4 * oct + r,
                    accY[ct][mt][r]);
  }
}

// ---------------- combine: y = Yacc/Z + 1e-8*SumV -> Yt bf16 (padded) ------
__global__ __launch_bounds__(256) void yt_epilogue(
    const float* __restrict__ Yacc, const float* __restrict__ Zacc,
    const float* __restrict__ SumV, unsigned short* __restrict__ Yt) {
  int b = blockIdx.y;
  int p = blockIdx.x * 64 + (threadIdx.x >> 2);
  int cq = (threadIdx.x & 3) * 32;
  float rZ = 1.0f / Zacc[(size_t)b * NN + p];
  const float* ya = Yacc + ((size_t)b * NN + p) * CC + cq;
  const float* sv = SumV + b * CC + cq;
  int h = p >> 6, w = p & 63;
  unsigned short* yp = Yt + ((size_t)b * YTP + (size_t)(h + 1) * 66 + (w + 1)) * CC + cq;
#pragma unroll
  for (int i = 0; i < 32; i += 8) {
    float4 a0 = *(const float4*)(ya + i);
    float4 a1 = *(const float4*)(ya + i + 4);
    float4 v0 = *(const float4*)(sv + i);
    float4 v1 = *(const float4*)(sv + i + 4);
    uint4 o;
    o.x = (unsigned)f2bf(a0.x * rZ + 1e-8f * v0.x) | ((unsigned)f2bf(a0.y * rZ + 1e-8f * v0.y) << 16);
    o.y = (unsigned)f2bf(a0.z * rZ + 1e-8f * v0.z) | ((unsigned)f2bf(a0.w * rZ + 1e-8f * v0.w) << 16);
    o.z = (unsigned)f2bf(a1.x * rZ + 1e-8f * v1.x) | ((unsigned)f2bf(a1.y * rZ + 1e-8f * v1.y) << 16);
    o.w = (unsigned)f2bf(a1.z * rZ + 1e-8f * v1.z) | ((unsigned)f2bf(a1.w * rZ + 1e-8f * v1.w) << 16);
    *(uint4*)(yp + i) = o;
  }
}

// ---------------- MFMA 3x3 conv + bias + leaky + residual ------------------
__global__ __launch_bounds__(256, 2) void conv_mfma(
    const unsigned short* __restrict__ Yt, const unsigned short* __restrict__ Wt,
    const float* __restrict__ x, const float* __restrict__ lb,
    float* __restrict__ out) {
  int h = blockIdx.x;
  int by = blockIdx.y;
  int b = blockIdx.z;
  int t = threadIdx.x;
  int wave = t >> 6, lane = t & 63;
  int col = lane & 15, oct = lane >> 4;
  int pxt = wave & 1, cohalf = wave >> 1;
  int w0 = by * 32 + pxt * 16;
  const unsigned short* Yb = Yt + (size_t)b * YTP * CC;

  f32x4 acc[4];
#pragma unroll
  for (int ct = 0; ct < 4; ct++) acc[ct] = (f32x4)0.f;

#pragma unroll
  for (int tap = 0; tap < 9; tap++) {
    int dh = tap / 3 - 1, dw = tap % 3 - 1;
    const unsigned short* ybase =
        Yb + (size_t)((h + 1 + dh) * 66 + (w0 + 1 + dw + col)) * CC;
#pragma unroll
    for (int kc = 0; kc < 4; kc++) {
      bf16x8 Af = *(const bf16x8*)(ybase + 32 * kc + 8 * oct);
#pragma unroll
      for (int ct = 0; ct < 4; ct++) {
        bf16x8 Bf = *(const bf16x8*)(Wt +
            (size_t)(cohalf * 64 + 16 * ct + col) * 1152 + tap * 128 + 32 * kc + 8 * oct);
        acc[ct] = __builtin_amdgcn_mfma_f32_16x16x32_bf16(Af, Bf, acc[ct], 0, 0, 0);
      }
    }
  }
#pragma unroll
  for (int ct = 0; ct < 4; ct++) {
    int co = cohalf * 64 + 16 * ct + col;
    float bv = lb[co];
    int n = h * 64 + w0 + 4 * oct;
    size_t base = ((size_t)b * CC + co) * NN + n;
    float4 xi = *(const float4*)(x + base);
    float4 o;
    float z0 = acc[ct][0] + bv; o.x = ((z0 >= 0.f) ? z0 : 0.2f * z0) + xi.x;
    float z1 = acc[ct][1] + bv; o.y = ((z1 >= 0.f) ? z1 : 0.2f * z1) + xi.y;
    float z2 = acc[ct][2] + bv; o.z = ((z2 >= 0.f) ? z2 : 0.2f * z2) + xi.z;
    float z3 = acc[ct][3] + bv; o.w = ((z3 >= 0.f) ? z3 : 0.2f * z3) + xi.w;
    *(float4*)(out + base) = o;
  }
}

extern "C" void kernel_launch(void* const* d_in, const int* in_sizes, int n_in,
                              void* d_out, int out_size, void* d_ws, size_t ws_size,
                              hipStream_t stream) {
  const float* x    = (const float*)d_in[0];
  const float* q_w  = (const float*)d_in[1];
  const float* q_b  = (const float*)d_in[2];
  const float* v_w  = (const float*)d_in[3];
  const float* v_b  = (const float*)d_in[4];
  const float* lw1w = (const float*)d_in[5];
  const float* lw1b = (const float*)d_in[6];
  const float* lw2w = (const float*)d_in[7];
  const float* lw2b = (const float*)d_in[8];
  const float* bw1w = (const float*)d_in[9];
  const float* bw1b = (const float*)d_in[10];
  const float* bw2w = (const float*)d_in[11];
  const float* bw2b = (const float*)d_in[12];
  const float* linw = (const float*)d_in[13];
  const float* linb = (const float*)d_in[14];
  float* out = (float*)d_out;

  const size_t BCN = (size_t)BB * CC * NN;  // 2,097,152
  const size_t BN  = (size_t)BB * NN;       // 16,384

  float* W = (float*)d_ws;
  float* qbuf = W;                                         // BCN f32 (later: Yacc overlay)
  unsigned short* vb16 = (unsigned short*)(qbuf + BCN);    // BCN bf16
  unsigned short* qt   = vb16 + BCN;                       // BCN bf16
  unsigned short* qtn  = qt + BCN;                         // BCN bf16
  unsigned short* Yt   = qtn + BCN;                        // BB*YTP*CC bf16
  unsigned short* Wt   = Yt + (size_t)BB * YTP * CC;       // CC*1152 bf16
  float* wmap = (float*)(Wt + (size_t)CC * 1152);
  float* bmap = wmap + BN;
  float* nrmb = bmap + BN;
  float* SumV = nrmb + BN;                                 // BB*CC
  float* Skey = SumV + (size_t)BB * CC;                    // BB*CC
  float* Zacc = Skey + (size_t)BB * CC;                    // BN
  float* Yacc = qbuf;                                      // overlay (qbuf dead after prep)

  hipMemsetAsync(SumV, 0, (size_t)BB * CC * sizeof(float), stream);
  hipMemsetAsync(Skey, 0, (size_t)BB * CC * sizeof(float), stream);
  hipMemsetAsync(Zacc, 0, BN * sizeof(float), stream);
  hipMemsetAsync(Yt, 0, (size_t)BB * YTP * CC * sizeof(unsigned short), stream);

  hipLaunchKernelGGL(qv_kernel, dim3(256), dim3(256), 0, stream,
                     x, q_w, q_b, v_w, v_b, qbuf, vb16, SumV);
  hipLaunchKernelGGL(heads_kernel, dim3(256), dim3(256), 0, stream,
                     qbuf, lw1w, lw1b, lw2w, lw2b, bw1w, bw1b, bw2w, bw2b,
                     wmap, bmap, nrmb);
  hipLaunchKernelGGL(prep_kernel, dim3(NN / 64, BB), dim3(256), 0, stream,
                     qbuf, nrmb, qt, qtn, Skey);
  hipLaunchKernelGGL(wrepack_kernel, dim3((CC * 1152 + 255) / 256), dim3(256), 0,
                     stream, linw, Wt);
  // qbuf now dead -> becomes Yacc
  hipMemsetAsync(Yacc, 0, BCN * sizeof(float), stream);
  hipLaunchKernelGGL(fused_attn, dim3(NN / 32, KSL, BB), dim3(256), 0, stream,
                     qt, qtn, vb16, nrmb, wmap, bmap, Skey, Zacc, Yacc);
  hipLaunchKernelGGL(yt_epilogue, dim3(NN / 64, BB), dim3(256), 0, stream,
                     Yacc, Zacc, SumV, Yt);
  hipLaunchKernelGGL(conv_mfma, dim3(HH, 2, BB), dim3(256), 0, stream,
                     Yt, Wt, x, linb, out);
}

// Round 5
// 326.511 us; speedup vs baseline: 4.4988x; 1.0351x over previous
//
#include <hip/hip_runtime.h>
#include <math.h>

#define BB 4
#define CC 128
#define NN 4096
#define HH 64
#define WW 64
#define MIDC 32
#define YTP 4356   // 66*66 padded pixel count
#define METAMAX 65536

typedef __attribute__((ext_vector_type(8))) short bf16x8;
typedef __attribute__((ext_vector_type(4))) float f32x4;

__device__ inline unsigned short f2bf(float f) {
  unsigned int u = __float_as_uint(f);
  unsigned int r = (u + 0x7FFFu + ((u >> 16) & 1u)) >> 16;
  return (unsigned short)r;
}
__device__ inline float bf2f(short s) {
  union { unsigned u; float f; } x;
  x.u = ((unsigned)(unsigned short)s) << 16;
  return x.f;
}

// ---------------- A1: q/v 1x1 convs (q fp32, v bf16) + SumV ----------------
// grid (256, 2): y=0 -> q head, y=1 -> v head; 64 px x 128 co per block
__global__ __launch_bounds__(256) void qv_kernel(
    const float* __restrict__ x,
    const float* __restrict__ qw, const float* __restrict__ qb,
    const float* __restrict__ vw, const float* __restrict__ vb,
    float* __restrict__ qbuf, unsigned short* __restrict__ vbuf,
    float* __restrict__ SumV) {
  int p0 = blockIdx.x * 64;
  int b = p0 / NN, n0 = p0 % NN;
  int head = blockIdx.y;
  const float* w = head ? vw : qw;
  int t = threadIdx.x;
  __shared__ float xs[CC][68];    // pad 68: 16B-aligned rows for float4
  __shared__ float wsh[16][132];  // pad 132: 16B-aligned rows
  int j = t & 15;   // pixel quad
  int g = t >> 4;   // co group (8 co)
  for (int l = 0; l < 32; l++) {
    int idx = t + 256 * l;
    int px = idx & 63, c = idx >> 6;
    xs[c][px] = x[((size_t)b * CC + c) * NN + n0 + px];
  }
  float acc[8][4];
  for (int i = 0; i < 8; i++)
    for (int p = 0; p < 4; p++) acc[i][p] = 0.f;
  for (int kc = 0; kc < CC; kc += 16) {
    __syncthreads();
    for (int l = 0; l < 8; l++) {
      int idx = t + 256 * l;
      int kk = idx & 15, co = idx >> 4;
      wsh[kk][co] = w[co * CC + kc + kk];
    }
    __syncthreads();
    for (int kk = 0; kk < 16; kk++) {
      float4 xv = *(const float4*)&xs[kc + kk][4 * j];
      float4 w0 = *(const float4*)&wsh[kk][8 * g];
      float4 w1 = *(const float4*)&wsh[kk][8 * g + 4];
      float xa[4] = {xv.x, xv.y, xv.z, xv.w};
      float wa[8] = {w0.x, w0.y, w0.z, w0.w, w1.x, w1.y, w1.z, w1.w};
#pragma unroll
      for (int i = 0; i < 8; i++)
#pragma unroll
        for (int p = 0; p < 4; p++) acc[i][p] += wa[i] * xa[p];
    }
  }
  for (int i = 0; i < 8; i++) {
    int co = 8 * g + i;
    if (head == 0) {
      float bias = qb[co];
      float* dst = qbuf + ((size_t)b * CC + co) * NN;
      float4 o = make_float4(acc[i][0] + bias, acc[i][1] + bias,
                             acc[i][2] + bias, acc[i][3] + bias);
      *(float4*)(dst + n0 + 4 * j) = o;
    } else {
      float bias = vb[co];
      float v0 = acc[i][0] + bias, v1 = acc[i][1] + bias;
      float v2 = acc[i][2] + bias, v3 = acc[i][3] + bias;
      unsigned short* dst = vbuf + ((size_t)b * CC + co) * NN + n0 + 4 * j;
      uint2 pk;
      pk.x = (unsigned int)f2bf(v0) | ((unsigned int)f2bf(v1) << 16);
      pk.y = (unsigned int)f2bf(v2) | ((unsigned int)f2bf(v3) << 16);
      *(uint2*)dst = pk;
      float s4 = (v0 + v1) + (v2 + v3);
      for (int d = 1; d < 16; d <<= 1) s4 += __shfl_xor(s4, d);
      if (j == 0) atomicAdd(&SumV[b * CC + co], s4);
    }
  }
}

// ------- A2: norms + heads + (merged prep): qt/qtn transpose + Skey --------
__global__ __launch_bounds__(256) void heads_kernel(
    const float* __restrict__ qbuf,
    const float* __restrict__ lw1w, const float* __restrict__ lw1b,
    const float* __restrict__ lw2w, const float* __restrict__ lw2b,
    const float* __restrict__ bw1w, const float* __restrict__ bw1b,
    const float* __restrict__ bw2w, const float* __restrict__ bw2b,
    float* __restrict__ wmap, float* __restrict__ bmap, float* __restrict__ nrm,
    unsigned short* __restrict__ qt, unsigned short* __restrict__ qtn,
    float* __restrict__ Skey) {
  int p0 = blockIdx.x * 64;
  int b = p0 / NN, n0 = p0 % NN;
  int t = threadIdx.x;
  __shared__ float xs[CC][65];
  __shared__ float hw[MIDC][CC];
  __shared__ float hb1[MIDC];
  __shared__ float hw2[MIDC];
  __shared__ float red[4][64];
  __shared__ float nrmS[64];
  for (int l = 0; l < 32; l++) {
    int idx = t + 256 * l;
    int px = idx & 63, c = idx >> 6;
    xs[c][px] = qbuf[((size_t)b * CC + c) * NN + n0 + px];
  }
  __syncthreads();
  int px = t & 63, g = t >> 6;
  float ssq = 0.f;
  for (int c = 32 * g; c < 32 * g + 32; c++) { float v = xs[c][px]; ssq += v * v; }
  red[g][px] = ssq;
  __syncthreads();
  if (g == 0) {
    float s = red[0][px] + red[1][px] + red[2][px] + red[3][px];
    float nm = fmaxf(sqrtf(s), 1e-4f);
    nrm[(size_t)b * NN + n0 + px] = nm;
    nrmS[px] = nm;
  }
  __syncthreads();
  // merged prep: transpose q -> qt / qtn, accumulate Skey
  {
    int n = t & 63, chalf = t >> 6;
    float sc = 1.0f / nrmS[n];
    unsigned int* q32 = (unsigned int*)qt;
    unsigned int* qn32 = (unsigned int*)qtn;
    size_t rowbase = ((size_t)b * NN + n0 + n) * CC + 32 * chalf;
    float skv[32];
#pragma unroll
    for (int i = 0; i < 32; i += 2) {
      float a0 = xs[32 * chalf + i][n], a1 = xs[32 * chalf + i + 1][n];
      unsigned short u0 = f2bf(a0 * sc), u1 = f2bf(a1 * sc);
      q32[(rowbase + i) >> 1] = (unsigned)f2bf(a0) | ((unsigned)f2bf(a1) << 16);
      qn32[(rowbase + i) >> 1] = (unsigned)u0 | ((unsigned)u1 << 16);
      skv[i] = bf2f((short)u0);
      skv[i + 1] = bf2f((short)u1);
    }
#pragma unroll
    for (int i = 0; i < 32; i++) {
      float v = skv[i];
      v += __shfl_xor(v, 1);  v += __shfl_xor(v, 2);
      v += __shfl_xor(v, 4);  v += __shfl_xor(v, 8);
      v += __shfl_xor(v, 16); v += __shfl_xor(v, 32);
      if ((t & 63) == 0) atomicAdd(Skey + b * CC + 32 * chalf + i, v);
    }
  }
  // weight / bias heads
  for (int head = 0; head < 2; head++) {
    const float* w1 = head ? bw1w : lw1w;
    const float* b1 = head ? bw1b : lw1b;
    const float* w2 = head ? bw2w : lw2w;
    const float* b2 = head ? bw2b : lw2b;
    __syncthreads();
    for (int idx = t; idx < MIDC * CC; idx += 256) {
      int c = idx & 127, m = idx >> 7;
      hw[m][c] = w1[m * CC + c];
    }
    if (t < MIDC) { hb1[t] = b1[t]; hw2[t] = w2[t]; }
    __syncthreads();
    float a[8];
    for (int mi = 0; mi < 8; mi++) a[mi] = hb1[8 * g + mi];
    for (int c = 0; c < CC; c++) {
      float xv = xs[c][px];
      for (int mi = 0; mi < 8; mi++) a[mi] += hw[8 * g + mi][c] * xv;
    }
    float part = 0.f;
    for (int mi = 0; mi < 8; mi++) {
      float z = a[mi];
      z = (z >= 0.f) ? z : 0.2f * z;
      part += hw2[8 * g + mi] * z;
    }
    red[g][px] = part;
    __syncthreads();
    if (g == 0) {
      float s = red[0][px] + red[1][px] + red[2][px] + red[3][px] + b2[0];
      (head ? bmap : wmap)[(size_t)b * NN + n0 + px] = s;
    }
  }
}

// ---------------- weight repack for 3x3 conv: Wt[co][tap][ci] bf16 ---------
__global__ __launch_bounds__(256) void wrepack_kernel(
    const float* __restrict__ lw, unsigned short* __restrict__ Wt) {
  int idx = blockIdx.x * 256 + threadIdx.x;
  if (idx >= CC * 1152) return;
  int co = idx / 1152, rem = idx % 1152;
  int tap = rem >> 7, ci = rem & 127;
  Wt[idx] = f2bf(lw[(size_t)(co * CC + ci) * 9 + tap]);
}

// ---------------- qk_sparse: QK^T + Z + compacted survivor tiles -----------
// grid 512: lin = mtile*16 + (b*4+ks); block = 128 m x 1024 keys
__global__ __launch_bounds__(256, 2) void qk_sparse(
    const unsigned short* __restrict__ qt, const unsigned short* __restrict__ qtn,
    const float* __restrict__ nrm, const float* __restrict__ wmap,
    const float* __restrict__ bmap, const float* __restrict__ Skey,
    float* __restrict__ Zacc, unsigned short* __restrict__ Tb,
    int* __restrict__ meta, int* __restrict__ cnt, int cap) {
  int lin = blockIdx.x;
  int mtile = lin >> 4;
  int bks = lin & 15;
  int b = bks >> 2, ks = bks & 3;
  int t = threadIdx.x, wave = t >> 6, lane = t & 63;
  int col = lane & 15, oct = lane >> 4;
  int m0 = mtile * 128 + 32 * wave;

  __shared__ unsigned short Bt[2][4096];     // frag-major B tiles (8 KB each)
  __shared__ unsigned short tS[4][32][40];   // per-wave survivor transform

  const unsigned short* qtb  = qt  + (size_t)b * NN * CC;
  const unsigned short* qtnb = qtn + (size_t)b * NN * CC;

  // persistent A fragments: raw q rows m0..m0+31
  bf16x8 A[2][4];
#pragma unroll
  for (int mt = 0; mt < 2; mt++)
#pragma unroll
    for (int kc = 0; kc < 4; kc++)
      A[mt][kc] = *(const bf16x8*)(qtb + (size_t)(m0 + 16 * mt + col) * CC + 32 * kc + 8 * oct);

  // analytic rowsum -> per-row stats c1, zd
  float stc1[2][4], stzd[2][4];
#pragma unroll
  for (int mt = 0; mt < 2; mt++) {
    float dot = 0.f;
#pragma unroll
    for (int kc = 0; kc < 4; kc++) {
      const float* skp = Skey + b * CC + 32 * kc + 8 * oct;
      float4 s0 = *(const float4*)skp;
      float4 s1 = *(const float4*)(skp + 4);
      bf16x8 a = A[mt][kc];
      dot += bf2f(a[0]) * s0.x + bf2f(a[1]) * s0.y + bf2f(a[2]) * s0.z + bf2f(a[3]) * s0.w;
      dot += bf2f(a[4]) * s1.x + bf2f(a[5]) * s1.y + bf2f(a[6]) * s1.z + bf2f(a[7]) * s1.w;
    }
    dot += __shfl_xor(dot, 16);
    dot += __shfl_xor(dot, 32);
    int m = m0 + 16 * mt + col;
    float c1 = dot * (1.0f / NN) * wmap[(size_t)b * NN + m] - bmap[(size_t)b * NN + m];
    float nm = nrm[(size_t)b * NN + m];
    float zd = nm * fmaxf(nm - c1, 0.f);   // analytic max of z (Cauchy-Schwarz)
#pragma unroll
    for (int r = 0; r < 4; r++) {
      stc1[mt][r] = __shfl(c1, 4 * oct + r);
      stzd[mt][r] = __shfl(zd, 4 * oct + r);
    }
  }

  int n0base = ks * 1024;
  // prologue: stage tile 0 into buf 0 (frag-major: frag f at f*1024B, lane*16B)
  {
    int f0 = wave, f1 = wave + 4;
    uint4 r0 = *(const uint4*)(qtnb + (size_t)(n0base + 16 * (f0 >> 2) + col) * CC + (4 * (f0 & 3) + oct) * 8);
    uint4 r1 = *(const uint4*)(qtnb + (size_t)(n0base + 16 * (f1 >> 2) + col) * CC + (4 * (f1 & 3) + oct) * 8);
    *(uint4*)&Bt[0][f0 * 512 + lane * 8] = r0;
    *(uint4*)&Bt[0][f1 * 512 + lane * 8] = r1;
  }
  __syncthreads();

  float zp[2][4];
#pragma unroll
  for (int mt = 0; mt < 2; mt++)
#pragma unroll
    for (int r = 0; r < 4; r++) zp[mt][r] = 0.f;
  bool didwork = false;

  for (int it = 0; it < 32; it++) {
    int cur = it & 1;
    bool more = (it + 1 < 32);
    uint4 r0, r1;
    if (more) {
      int n0n = n0base + (it + 1) * 32;
      int f0 = wave, f1 = wave + 4;
      r0 = *(const uint4*)(qtnb + (size_t)(n0n + 16 * (f0 >> 2) + col) * CC + (4 * (f0 & 3) + oct) * 8);
      r1 = *(const uint4*)(qtnb + (size_t)(n0n + 16 * (f1 >> 2) + col) * CC + (4 * (f1 & 3) + oct) * 8);
    }
    // compute on current tile
    f32x4 acc[2][2];
    acc[0][0] = (f32x4)0.f; acc[0][1] = (f32x4)0.f;
    acc[1][0] = (f32x4)0.f; acc[1][1] = (f32x4)0.f;
#pragma unroll
    for (int nt = 0; nt < 2; nt++)
#pragma unroll
      for (int kc = 0; kc < 4; kc++) {
        bf16x8 Bf = *(const bf16x8*)&Bt[cur][(nt * 4 + kc) * 512 + lane * 8];
        acc[0][nt] = __builtin_amdgcn_mfma_f32_16x16x32_bf16(A[0][kc], Bf, acc[0][nt], 0, 0, 0);
        acc[1][nt] = __builtin_amdgcn_mfma_f32_16x16x32_bf16(A[1][kc], Bf, acc[1][nt], 0, 0, 0);
      }
    float d[2][2][4];
    float fm = -1e30f;
#pragma unroll
    for (int mt = 0; mt < 2; mt++)
#pragma unroll
      for (int nt = 0; nt < 2; nt++)
#pragma unroll
        for (int r = 0; r < 4; r++) {
          float l = acc[mt][nt][r];
          float z = l * fmaxf(l - stc1[mt][r], 0.f);
          float dd = z - stzd[mt][r];
          d[mt][nt][r] = dd;
          fm = fmaxf(fm, dd);
        }
    if (__any(fm > -18.4207f)) {   // survivor tile (e^-18.42 = 1e-8)
      didwork = true;
      int n0 = n0base + it * 32;
      // note: s<=0 => z=0 => d=-zd => expf(d)=e^{-zd} (the exact Z term); T entry masked to 0
#pragma unroll
      for (int mt = 0; mt < 2; mt++)
#pragma unroll
        for (int nt = 0; nt < 2; nt++)
#pragma unroll
          for (int r = 0; r < 4; r++) {
            float s = acc[mt][nt][r] - stc1[mt][r];
            float e = __expf(d[mt][nt][r]);
            zp[mt][r] += e;
            tS[wave][16 * mt + 4 * oct + r][16 * nt + col] = f2bf((s > 0.f) ? e : 0.f);
          }
      int slot;
      if (lane == 0) slot = atomicAdd(cnt, 1);
      slot = __shfl(slot, 0);
      if (slot < cap) {
        if (lane == 0) meta[slot] = (b << 14) | ((m0 >> 5) << 7) | (n0 >> 5);
        const unsigned short* src = &tS[wave][lane >> 1][(lane & 1) * 16];
        unsigned short* dst = Tb + (size_t)slot * 1024 + (lane >> 1) * 32 + (lane & 1) * 16;
        *(uint4*)dst = *(const uint4*)src;
        *(uint4*)(dst + 8) = *(const uint4*)(src + 8);
      }
    }
    if (more) {
      int nxt = cur ^ 1;
      *(uint4*)&Bt[nxt][wave * 512 + lane * 8] = r0;
      *(uint4*)&Bt[nxt][(wave + 4) * 512 + lane * 8] = r1;
    }
    __syncthreads();
  }

  if (didwork) {
#pragma unroll
    for (int mt = 0; mt < 2; mt++)
#pragma unroll
      for (int r = 0; r < 4; r++) {
        float v = zp[mt][r];
        v += __shfl_xor(v, 1); v += __shfl_xor(v, 2);
        v += __shfl_xor(v, 4); v += __shfl_xor(v, 8);
        if (col == 0)
          atomicAdd(Zacc + (size_t)b * NN + m0 + 16 * mt + 4 * oct + r, v);
      }
  }
}

// ---------------- pv: process survivor tiles -> Yacc atomics ---------------
__global__ __launch_bounds__(256) void pv_kernel(
    const unsigned short* __restrict__ vb16, const unsigned short* __restrict__ Tb,
    const int* __restrict__ meta, const int* __restrict__ cnt, int cap,
    float* __restrict__ Yacc) {
  int n = *cnt;
  if (n > cap) n = cap;
  int t = threadIdx.x, wave = t >> 6, lane = t & 63;
  int col = lane & 15, oct = lane >> 4;
  for (int slot = blockIdx.x; slot < n; slot += gridDim.x) {
    int mv = meta[slot];
    int b = mv >> 14, m0 = ((mv >> 7) & 127) * 32, n0 = (mv & 127) * 32;
    const unsigned short* Vb = vb16 + (size_t)b * CC * NN;
    const unsigned short* Tp = Tb + (size_t)slot * 1024;
    bf16x8 Bf[2];
#pragma unroll
    for (int bt = 0; bt < 2; bt++)
      Bf[bt] = *(const bf16x8*)(Tp + (16 * bt + col) * 32 + 8 * oct);
    f32x4 acc[2][2];
    acc[0][0] = (f32x4)0.f; acc[0][1] = (f32x4)0.f;
    acc[1][0] = (f32x4)0.f; acc[1][1] = (f32x4)0.f;
#pragma unroll
    for (int ct = 0; ct < 2; ct++) {
      bf16x8 Af = *(const bf16x8*)(Vb + (size_t)(32 * wave + 16 * ct + col) * NN + n0 + 8 * oct);
#pragma unroll
      for (int bt = 0; bt < 2; bt++)
        acc[ct][bt] = __builtin_amdgcn_mfma_f32_16x16x32_bf16(Af, Bf[bt], acc[ct][bt], 0, 0, 0);
    }
#pragma unroll
    for (int ct = 0; ct < 2; ct++)
#pragma unroll
      for (int bt = 0; bt < 2; bt++)
#pragma unroll
        for (int r = 0; r < 4; r++)
          atomicAdd(Yacc + ((size_t)b * NN + m0 + 16 * bt + col) * CC +
                        32 * wave + 16 * ct + 4 * oct + r,
                    acc[ct][bt][r]);
  }
}

// ---------------- combine: y = Yacc/Z + 1e-8*SumV -> Yt bf16 (padded) ------
__global__ __launch_bounds__(256) void yt_epilogue(
    const float* __restrict__ Yacc, const float* __restrict__ Zacc,
    const float* __restrict__ SumV, unsigned short* __restrict__ Yt) {
  int b = blockIdx.y;
  int p = blockIdx.x * 64 + (threadIdx.x >> 2);
  int cq = (threadIdx.x & 3) * 32;
  float rZ = 1.0f / Zacc[(size_t)b * NN + p];
  const float* ya = Yacc + ((size_t)b * NN + p) * CC + cq;
  const float* sv = SumV + b * CC + cq;
  int h = p >> 6, w = p & 63;
  unsigned short* yp = Yt + ((size_t)b * YTP + (size_t)(h + 1) * 66 + (w + 1)) * CC + cq;
#pragma unroll
  for (int i = 0; i < 32; i += 8) {
    float4 a0 = *(const float4*)(ya + i);
    float4 a1 = *(const float4*)(ya + i + 4);
    float4 v0 = *(const float4*)(sv + i);
    float4 v1 = *(const float4*)(sv + i + 4);
    uint4 o;
    o.x = (unsigned)f2bf(a0.x * rZ + 1e-8f * v0.x) | ((unsigned)f2bf(a0.y * rZ + 1e-8f * v0.y) << 16);
    o.y = (unsigned)f2bf(a0.z * rZ + 1e-8f * v0.z) | ((unsigned)f2bf(a0.w * rZ + 1e-8f * v0.w) << 16);
    o.z = (unsigned)f2bf(a1.x * rZ + 1e-8f * v1.x) | ((unsigned)f2bf(a1.y * rZ + 1e-8f * v1.y) << 16);
    o.w = (unsigned)f2bf(a1.z * rZ + 1e-8f * v1.z) | ((unsigned)f2bf(a1.w * rZ + 1e-8f * v1.w) << 16);
    *(uint4*)(yp + i) = o;
  }
}

// ---------------- MFMA 3x3 conv + bias + leaky + residual ------------------
__global__ __launch_bounds__(256, 2) void conv_mfma(
    const unsigned short* __restrict__ Yt, const unsigned short* __restrict__ Wt,
    const float* __restrict__ x, const float* __restrict__ lb,
    float* __restrict__ out) {
  int h = blockIdx.x;
  int by = blockIdx.y;
  int b = blockIdx.z;
  int t = threadIdx.x;
  int wave = t >> 6, lane = t & 63;
  int col = lane & 15, oct = lane >> 4;
  int pxt = wave & 1, cohalf = wave >> 1;
  int w0 = by * 32 + pxt * 16;
  const unsigned short* Yb = Yt + (size_t)b * YTP * CC;

  f32x4 acc[4];
#pragma unroll
  for (int ct = 0; ct < 4; ct++) acc[ct] = (f32x4)0.f;

#pragma unroll
  for (int tap = 0; tap < 9; tap++) {
    int dh = tap / 3 - 1, dw = tap % 3 - 1;
    const unsigned short* ybase =
        Yb + (size_t)((h + 1 + dh) * 66 + (w0 + 1 + dw + col)) * CC;
#pragma unroll
    for (int kc = 0; kc < 4; kc++) {
      bf16x8 Af = *(const bf16x8*)(ybase + 32 * kc + 8 * oct);
#pragma unroll
      for (int ct = 0; ct < 4; ct++) {
        bf16x8 Bf = *(const bf16x8*)(Wt +
            (size_t)(cohalf * 64 + 16 * ct + col) * 1152 + tap * 128 + 32 * kc + 8 * oct);
        acc[ct] = __builtin_amdgcn_mfma_f32_16x16x32_bf16(Af, Bf, acc[ct], 0, 0, 0);
      }
    }
  }
#pragma unroll
  for (int ct = 0; ct < 4; ct++) {
    int co = cohalf * 64 + 16 * ct + col;
    float bv = lb[co];
    int n = h * 64 + w0 + 4 * oct;
    size_t base = ((size_t)b * CC + co) * NN + n;
    float4 xi = *(const float4*)(x + base);
    float4 o;
    float z0 = acc[ct][0] + bv; o.x = ((z0 >= 0.f) ? z0 : 0.2f * z0) + xi.x;
    float z1 = acc[ct][1] + bv; o.y = ((z1 >= 0.f) ? z1 : 0.2f * z1) + xi.y;
    float z2 = acc[ct][2] + bv; o.z = ((z2 >= 0.f) ? z2 : 0.2f * z2) + xi.z;
    float z3 = acc[ct][3] + bv; o.w = ((z3 >= 0.f) ? z3 : 0.2f * z3) + xi.w;
    *(float4*)(out + base) = o;
  }
}

extern "C" void kernel_launch(void* const* d_in, const int* in_sizes, int n_in,
                              void* d_out, int out_size, void* d_ws, size_t ws_size,
                              hipStream_t stream) {
  const float* x    = (const float*)d_in[0];
  const float* q_w  = (const float*)d_in[1];
  const float* q_b  = (const float*)d_in[2];
  const float* v_w  = (const float*)d_in[3];
  const float* v_b  = (const float*)d_in[4];
  const float* lw1w = (const float*)d_in[5];
  const float* lw1b = (const float*)d_in[6];
  const float* lw2w = (const float*)d_in[7];
  const float* lw2b = (const float*)d_in[8];
  const float* bw1w = (const float*)d_in[9];
  const float* bw1b = (const float*)d_in[10];
  const float* bw2w = (const float*)d_in[11];
  const float* bw2b = (const float*)d_in[12];
  const float* linw = (const float*)d_in[13];
  const float* linb = (const float*)d_in[14];
  float* out = (float*)d_out;

  const size_t BCN = (size_t)BB * CC * NN;  // 2,097,152
  const size_t BN  = (size_t)BB * NN;       // 16,384

  float* W = (float*)d_ws;
  float* qbuf = W;                                         // BCN f32; Yacc overlay later
  unsigned short* vb16 = (unsigned short*)(qbuf + BCN);    // BCN bf16
  unsigned short* qt   = vb16 + BCN;                       // BCN bf16
  unsigned short* qtn  = qt + BCN;                         // BCN bf16
  unsigned short* Yt   = qtn + BCN;                        // BB*YTP*CC bf16
  unsigned short* Wt   = Yt + (size_t)BB * YTP * CC;       // CC*1152 bf16
  float* wmap = (float*)(Wt + (size_t)CC * 1152);
  float* bmap = wmap + BN;
  float* nrmb = bmap + BN;
  float* SumV = nrmb + BN;                                 // BB*CC  } contiguous
  float* Skey = SumV + (size_t)BB * CC;                    // BB*CC  } zero
  float* Zacc = Skey + (size_t)BB * CC;                    // BN     } region
  int*   cnt  = (int*)(Zacc + BN);                         // 16     }
  int*   meta = cnt + 16;                                  // METAMAX ints
  unsigned short* Tb = (unsigned short*)(meta + METAMAX);
  float* Yacc = qbuf;

  size_t usedBytes = (size_t)((char*)Tb - (char*)W);
  int cap = 0;
  if (ws_size > usedBytes + 2048)
    cap = (int)((ws_size - usedBytes) / 2048);
  if (cap > METAMAX) cap = METAMAX;

  size_t zeroBytes = ((size_t)2 * BB * CC + BN + 16) * sizeof(float);
  hipMemsetAsync(SumV, 0, zeroBytes, stream);
  hipMemsetAsync(Yt, 0, (size_t)BB * YTP * CC * sizeof(unsigned short), stream);

  hipLaunchKernelGGL(qv_kernel, dim3(256, 2), dim3(256), 0, stream,
                     x, q_w, q_b, v_w, v_b, qbuf, vb16, SumV);
  hipLaunchKernelGGL(heads_kernel, dim3(256), dim3(256), 0, stream,
                     qbuf, lw1w, lw1b, lw2w, lw2b, bw1w, bw1b, bw2w, bw2b,
                     wmap, bmap, nrmb, qt, qtn, Skey);
  hipLaunchKernelGGL(wrepack_kernel, dim3((CC * 1152 + 255) / 256), dim3(256), 0,
                     stream, linw, Wt);
  // qbuf dead -> Yacc
  hipMemsetAsync(Yacc, 0, BCN * sizeof(float), stream);
  hipLaunchKernelGGL(qk_sparse, dim3(512), dim3(256), 0, stream,
                     qt, qtn, nrmb, wmap, bmap, Skey, Zacc, Tb, meta, cnt, cap);
  hipLaunchKernelGGL(pv_kernel, dim3(256), dim3(256), 0, stream,
                     vb16, Tb, meta, cnt, cap, Yacc);
  hipLaunchKernelGGL(yt_epilogue, dim3(NN / 64, BB), dim3(256), 0, stream,
                     Yacc, Zacc, SumV, Yt);
  hipLaunchKernelGGL(conv_mfma, dim3(HH, 2, BB), dim3(256), 0, stream,
                     Yt, Wt, x, linb, out);
}